// Round 1
// baseline (578.310 us; speedup 1.0000x reference)
//
#include <hip/hip_runtime.h>
#include <hip/hip_bf16.h>
#include <stdint.h>

#define B_SZ   512
#define NINST  4
#define D_IN   1024
#define D_OUTD 1024
#define CCOMP  64
#define MRANK  256
#define KTOT   (CCOMP*MRANK)   // 16384

typedef __attribute__((ext_vector_type(4))) float  f32x4;
typedef __attribute__((ext_vector_type(8))) __bf16 bf16x8;
typedef __attribute__((ext_vector_type(4))) __bf16 bf16x4;

// ---------------------------------------------------------------------------
// Phase 1: inner[i][b][c*256+m] = mask[b][i][c] * sum_d x[b][i][d]*A[i][c][d][m]
// grid = I*C*8 blocks; per (i,c): 4 btiles(128) x 2 ntiles(128). BK=64.
// 256 threads = 4 waves (2x2), wave tile 64x64, mfma 16x16x32 bf16.
// Xs: linear [128][64] with XOR-chunk swizzle (conflict-free b128 reads).
// As: row-major [64][132] (k x m, padded); B-frags via 8x ds_read_u16.
// ---------------------------------------------------------------------------
__global__ __launch_bounds__(256, 2)
void p1_kernel(const float* __restrict__ x, const float* __restrict__ A,
               const int* __restrict__ mask, __bf16* __restrict__ inner)
{
  const int bid = blockIdx.x;
  const int ic  = bid >> 3;        // i*64 + c
  const int i   = ic >> 6;
  const int c   = ic & 63;
  const int bt  = (bid >> 1) & 3;
  const int nt  = bid & 1;
  const int b0  = bt * 128;
  const int m0  = nt * 128;

  const int tid  = threadIdx.x;
  const int lane = tid & 63;
  const int wid  = tid >> 6;
  const int wr   = wid >> 1;       // 0..1: row strip of 64
  const int wc   = wid & 1;        // 0..1: col strip of 64

  __shared__ __bf16 Xs[128][64];   // 16 KB, chunk-XOR swizzled
  __shared__ __bf16 As[64][132];   // 16.5 KB, k-major
  __shared__ int    Msk[128];

  if (tid < 128)
    Msk[tid] = mask[(size_t)(b0 + tid) * (NINST*CCOMP) + i*CCOMP + c];

  f32x4 acc[4][4];
#pragma unroll
  for (int a_ = 0; a_ < 4; ++a_)
#pragma unroll
    for (int b_ = 0; b_ < 4; ++b_)
      acc[a_][b_] = (f32x4){0.f, 0.f, 0.f, 0.f};

  const float* xbase = x + ((size_t)b0 * NINST + i) * D_IN;   // row stride NINST*D_IN
  const float* Abase = A + (size_t)ic * D_IN * MRANK + m0;    // d stride MRANK

  for (int kt = 0; kt < D_IN/64; ++kt) {
    // ---- stage X tile: 128 rows x 64 k, fp32 -> bf16, swizzled ----
    {
      const int r  = tid >> 4;     // 0..15
      const int kc = tid & 15;     // float4 index within row (k = kc*4)
#pragma unroll
      for (int rr = 0; rr < 8; ++rr) {
        const int row = r + rr*16;
        f32x4 v = *(const f32x4*)(xbase + (size_t)row*(NINST*D_IN) + kt*64 + kc*4);
        bf16x4 h; h[0]=(__bf16)v.x; h[1]=(__bf16)v.y; h[2]=(__bf16)v.z; h[3]=(__bf16)v.w;
        const int chunk = (kc >> 1) ^ (row & 7);
        *(bf16x4*)(&Xs[row][chunk*8 + (kc & 1)*4]) = h;
      }
    }
    // ---- stage A tile: 64 k x 128 m (natural layout, coalesced) ----
    {
      const int mc = tid & 31;     // m = mc*4
      const int kr = tid >> 5;     // 0..7
#pragma unroll
      for (int rr = 0; rr < 8; ++rr) {
        const int k = kr + rr*8;
        f32x4 v = *(const f32x4*)(Abase + (size_t)(kt*64 + k)*MRANK + mc*4);
        bf16x4 h; h[0]=(__bf16)v.x; h[1]=(__bf16)v.y; h[2]=(__bf16)v.z; h[3]=(__bf16)v.w;
        *(bf16x4*)(&As[k][mc*4]) = h;
      }
    }
    __syncthreads();

#pragma unroll
    for (int kk = 0; kk < 2; ++kk) {
      bf16x8 af[4];
#pragma unroll
      for (int mi = 0; mi < 4; ++mi) {
        const int row = wr*64 + mi*16 + (lane & 15);
        const int chunk = (kk*4 + (lane >> 4)) ^ (row & 7);
        af[mi] = *(const bf16x8*)(&Xs[row][chunk*8]);
      }
#pragma unroll
      for (int ni = 0; ni < 4; ++ni) {
        const int col = wc*64 + ni*16 + (lane & 15);
        const int kb  = kk*32 + (lane >> 4)*8;
        bf16x8 bfr;
#pragma unroll
        for (int j = 0; j < 8; ++j) bfr[j] = As[kb + j][col];
#pragma unroll
        for (int mi = 0; mi < 4; ++mi)
          acc[mi][ni] = __builtin_amdgcn_mfma_f32_16x16x32_bf16(af[mi], bfr, acc[mi][ni], 0, 0, 0);
      }
    }
    __syncthreads();
  }

  // ---- epilogue: mask rows, store bf16 to inner[i][b][c*256+m] ----
  __bf16* obase = inner + ((size_t)i * B_SZ + b0) * KTOT + (size_t)c * MRANK + m0;
#pragma unroll
  for (int mi = 0; mi < 4; ++mi) {
#pragma unroll
    for (int ni = 0; ni < 4; ++ni) {
      const int colL = wc*64 + ni*16 + (lane & 15);
#pragma unroll
      for (int j = 0; j < 4; ++j) {
        const int rowL = wr*64 + mi*16 + (lane >> 4)*4 + j;
        const float mval = (float)Msk[rowL];
        obase[(size_t)rowL * KTOT + colL] = (__bf16)(acc[mi][ni][j] * mval);
      }
    }
  }
}

// ---------------------------------------------------------------------------
// Phase 2: out[b][i][o] = sum_K inner[i][b][K] * Bflat[i][K][o],  K = 16384
// grid = I*16*8 = 512 blocks; tile 64(b) x 64(o), BK=64; 4 waves (2x2),
// wave tile 32x32. inner staged direct-to-LDS (pre-swizzled src),
// B fp32->bf16 reg-staged; B-frags via ds_read_u16 on padded row-major LDS.
// ---------------------------------------------------------------------------
__device__ inline void gload_lds16(const __bf16* g, __bf16* l) {
  __builtin_amdgcn_global_load_lds(
      (const __attribute__((address_space(1))) void*)g,
      (__attribute__((address_space(3))) void*)l, 16, 0, 0);
}

__global__ __launch_bounds__(256, 2)
void p2_kernel(const __bf16* __restrict__ inner, const float* __restrict__ Bm,
               float* __restrict__ out)
{
  const int bid = blockIdx.x;
  const int bt  = bid & 7;         // consecutive bids share the B o-panel
  const int nt  = (bid >> 3) & 15;
  const int i   = bid >> 7;
  const int b0  = bt * 64;
  const int o0  = nt * 64;

  const int tid  = threadIdx.x;
  const int lane = tid & 63;
  const int wid  = tid >> 6;
  const int wr   = wid >> 1;
  const int wc   = wid & 1;

  __shared__ __bf16 Is[64][64];    // 8 KB, chunk-XOR swizzled (via src)
  __shared__ __bf16 Bs[64][68];    // 8.5 KB, k-major padded

  f32x4 acc[2][2];
#pragma unroll
  for (int a_ = 0; a_ < 2; ++a_)
#pragma unroll
    for (int b_ = 0; b_ < 2; ++b_)
      acc[a_][b_] = (f32x4){0.f, 0.f, 0.f, 0.f};

  const __bf16* ibase = inner + ((size_t)i * B_SZ + b0) * KTOT;
  const float*  Bbase = Bm + (size_t)i * KTOT * D_OUTD + o0;

  for (int kt = 0; kt < KTOT/64; ++kt) {
    // ---- stage inner tile 64x64 bf16 via global_load_lds (16B/lane) ----
#pragma unroll
    for (int q = 0; q < 2; ++q) {
      const int ci  = q*4 + wid;               // 0..7, wave-uniform
      const int row = ci*8 + (lane >> 3);
      const int kch = (lane & 7) ^ (row & 7);  // pre-swizzle the source
      gload_lds16(ibase + (size_t)row * KTOT + kt*64 + kch*8,
                  &Is[0][0] + ci*512);
    }
    // ---- stage B tile 64 k x 64 o, fp32 -> bf16 ----
    {
      const int oc = tid & 15;
      const int kr = tid >> 4;
#pragma unroll
      for (int rr = 0; rr < 4; ++rr) {
        const int k = kr + rr*16;
        f32x4 v = *(const f32x4*)(Bbase + (size_t)(kt*64 + k)*D_OUTD + oc*4);
        bf16x4 h; h[0]=(__bf16)v.x; h[1]=(__bf16)v.y; h[2]=(__bf16)v.z; h[3]=(__bf16)v.w;
        *(bf16x4*)(&Bs[k][oc*4]) = h;
      }
    }
    __syncthreads();

#pragma unroll
    for (int kk = 0; kk < 2; ++kk) {
      bf16x8 af[2];
#pragma unroll
      for (int mi = 0; mi < 2; ++mi) {
        const int row = wr*32 + mi*16 + (lane & 15);
        const int chunk = (kk*4 + (lane >> 4)) ^ (row & 7);
        af[mi] = *(const bf16x8*)(&Is[row][chunk*8]);
      }
#pragma unroll
      for (int ni = 0; ni < 2; ++ni) {
        const int col = wc*32 + ni*16 + (lane & 15);
        const int kb  = kk*32 + (lane >> 4)*8;
        bf16x8 bfr;
#pragma unroll
        for (int j = 0; j < 8; ++j) bfr[j] = Bs[kb + j][col];
#pragma unroll
        for (int mi = 0; mi < 2; ++mi)
          acc[mi][ni] = __builtin_amdgcn_mfma_f32_16x16x32_bf16(af[mi], bfr, acc[mi][ni], 0, 0, 0);
      }
    }
    __syncthreads();
  }

  // ---- epilogue: fp32 store to out[b][i][o] ----
  float* obase = out + ((size_t)b0 * NINST + i) * D_OUTD + o0;
#pragma unroll
  for (int mi = 0; mi < 2; ++mi) {
#pragma unroll
    for (int ni = 0; ni < 2; ++ni) {
      const int colL = wc*32 + ni*16 + (lane & 15);
#pragma unroll
      for (int j = 0; j < 4; ++j) {
        const int rowL = wr*32 + mi*16 + (lane >> 4)*4 + j;
        obase[(size_t)rowL * (NINST*D_OUTD) + colL] = acc[mi][ni][j];
      }
    }
  }
}

extern "C" void kernel_launch(void* const* d_in, const int* in_sizes, int n_in,
                              void* d_out, int out_size, void* d_ws, size_t ws_size,
                              hipStream_t stream) {
  const float* x    = (const float*)d_in[0];
  const float* A    = (const float*)d_in[1];
  const float* Bm   = (const float*)d_in[2];
  const int*   mask = (const int*)d_in[3];
  __bf16* inner = (__bf16*)d_ws;   // needs 512*4*64*256*2 = 64 MB

  p1_kernel<<<dim3(NINST*CCOMP*8), dim3(256), 0, stream>>>(x, A, mask, inner);
  p2_kernel<<<dim3(NINST*16*8),    dim3(256), 0, stream>>>(inner, Bm, (float*)d_out);
}

// Round 2
// 526.316 us; speedup vs baseline: 1.0988x; 1.0988x over previous
//
#include <hip/hip_runtime.h>
#include <hip/hip_bf16.h>
#include <stdint.h>

#define B_SZ   512
#define NINST  4
#define D_IN   1024
#define D_OUTD 1024
#define CCOMP  64
#define MRANK  256
#define KTOT   (CCOMP*MRANK)   // 16384

typedef __attribute__((ext_vector_type(4))) float  f32x4;
typedef __attribute__((ext_vector_type(8))) __bf16 bf16x8;
typedef __attribute__((ext_vector_type(4))) __bf16 bf16x4;

__device__ inline void gload_lds16(const __bf16* g, __bf16* l) {
  __builtin_amdgcn_global_load_lds(
      (const __attribute__((address_space(1))) void*)g,
      (__attribute__((address_space(3))) void*)l, 16, 0, 0);
}

// ---------------------------------------------------------------------------
// Phase 1: inner[i][b][c*256+m] = mask[b][i][c] * sum_d x[b][i][d]*A[i][c][d][m]
// 2048 blocks (XCD-swizzled so the 8 subtiles of each (i,c) share an XCD/L2),
// 256 thr = 4 waves (2x2), tile 128b x 128m, BK=64.
// Xs: [128][64] bf16, chunk-XOR swizzle (validated in R0).
// As_t: [128 m][64 k] bf16, n-major + XOR swizzle -> B-frags are ds_read_b128.
// Staged via 32 coalesced scalar dword loads + 4 packed b128 LDS writes/thread.
// ---------------------------------------------------------------------------
__global__ __launch_bounds__(256, 4)
void p1_kernel(const float* __restrict__ x, const float* __restrict__ A,
               const int* __restrict__ mask, __bf16* __restrict__ inner)
{
  const int bid = blockIdx.x;
  const int L   = (bid & 7) * 256 + (bid >> 3);   // XCD-group: 8 subtiles/ic together
  const int ic  = L >> 3;
  const int i   = ic >> 6;
  const int c   = ic & 63;
  const int bt  = (L >> 1) & 3;
  const int nt  = L & 1;
  const int b0  = bt * 128;
  const int m0  = nt * 128;

  const int tid  = threadIdx.x;
  const int lane = tid & 63;
  const int wid  = tid >> 6;
  const int wr   = wid >> 1;
  const int wc   = wid & 1;

  __shared__ __bf16 Xs[128][64];     // 16 KB
  __shared__ __bf16 As_t[128][64];   // 16 KB, m-major
  __shared__ int    Msk[128];

  if (tid < 128)
    Msk[tid] = mask[(size_t)(b0 + tid) * (NINST*CCOMP) + i*CCOMP + c];

  f32x4 acc[4][4];
#pragma unroll
  for (int a_ = 0; a_ < 4; ++a_)
#pragma unroll
    for (int b_ = 0; b_ < 4; ++b_)
      acc[a_][b_] = (f32x4){0.f, 0.f, 0.f, 0.f};

  const float* xbase = x + ((size_t)b0 * NINST + i) * D_IN;
  const float* Abase = A + (size_t)ic * D_IN * MRANK + m0;

  const int am = tid & 127;          // A-stage: column m within tile
  const int ag = tid >> 7;           // 0..1 -> k-octet group

  for (int kt = 0; kt < D_IN/64; ++kt) {
    // ---- stage X tile: 128 x 64, fp32 -> bf16, swizzled (unchanged) ----
    {
      const int r  = tid >> 4;
      const int kc = tid & 15;
#pragma unroll
      for (int rr = 0; rr < 8; ++rr) {
        const int row = r + rr*16;
        f32x4 v = *(const f32x4*)(xbase + (size_t)row*(NINST*D_IN) + kt*64 + kc*4);
        bf16x4 h; h[0]=(__bf16)v.x; h[1]=(__bf16)v.y; h[2]=(__bf16)v.z; h[3]=(__bf16)v.w;
        const int chunk = (kc >> 1) ^ (row & 7);
        *(bf16x4*)(&Xs[row][chunk*8 + (kc & 1)*4]) = h;
      }
    }
    // ---- stage A tile TRANSPOSED: global [k][m] -> LDS [m][k] bf16 ----
#pragma unroll
    for (int q = 0; q < 4; ++q) {
      const int oct = ag*4 + q;      // k-octet 0..7
      float v[8];
#pragma unroll
      for (int j = 0; j < 8; ++j)
        v[j] = Abase[(size_t)(kt*64 + oct*8 + j)*MRANK + am];  // 256B coalesced
      bf16x8 h;
#pragma unroll
      for (int j = 0; j < 8; ++j) h[j] = (__bf16)v[j];
      *(bf16x8*)(&As_t[am][((oct ^ (am & 7)))*8]) = h;         // conflict-free
    }
    __syncthreads();

#pragma unroll
    for (int kk = 0; kk < 2; ++kk) {
      bf16x8 af[4];
#pragma unroll
      for (int mi = 0; mi < 4; ++mi) {
        const int row = wr*64 + mi*16 + (lane & 15);
        const int chunk = (kk*4 + (lane >> 4)) ^ (row & 7);
        af[mi] = *(const bf16x8*)(&Xs[row][chunk*8]);
      }
#pragma unroll
      for (int ni = 0; ni < 4; ++ni) {
        const int col = wc*64 + ni*16 + (lane & 15);
        const int chunk = (kk*4 + (lane >> 4)) ^ (col & 7);
        bf16x8 bfr = *(const bf16x8*)(&As_t[col][chunk*8]);    // single b128
#pragma unroll
        for (int mi = 0; mi < 4; ++mi)
          acc[mi][ni] = __builtin_amdgcn_mfma_f32_16x16x32_bf16(af[mi], bfr, acc[mi][ni], 0, 0, 0);
      }
    }
    __syncthreads();
  }

  // ---- epilogue: mask rows, store bf16 ----
  __bf16* obase = inner + ((size_t)i * B_SZ + b0) * KTOT + (size_t)c * MRANK + m0;
#pragma unroll
  for (int mi = 0; mi < 4; ++mi) {
#pragma unroll
    for (int ni = 0; ni < 4; ++ni) {
      const int colL = wc*64 + ni*16 + (lane & 15);
#pragma unroll
      for (int j = 0; j < 4; ++j) {
        const int rowL = wr*64 + mi*16 + (lane >> 4)*4 + j;
        const float mval = (float)Msk[rowL];
        obase[(size_t)rowL * KTOT + colL] = (__bf16)(acc[mi][ni][j] * mval);
      }
    }
  }
}

// ---------------------------------------------------------------------------
// Phase 2: out[b][i][o] = sum_K inner[i][b][K] * Bflat[i][K][o],  K = 16384
// 512 blocks (XCD-swizzled: the 8 bt-sharers of each B-panel on one XCD),
// 256 thr = 4 waves, tile 64b x 64o, BK=128, K-SPLIT across waves:
// wave w owns the full 64x64 C-tile over k-octets [w*4, w*4+4) of each step;
// cross-wave LDS reduction at the end. Halves LDS frag multiplicity.
// Is: [64][128] bf16 via global_load_lds (pre-swizzled source).
// Bs_t: [64 o][128 k] bf16 transposed + 16-chunk XOR swizzle.
// ---------------------------------------------------------------------------
__global__ __launch_bounds__(256, 4)
void p2_kernel(const __bf16* __restrict__ inner, const float* __restrict__ Bm,
               float* __restrict__ out)
{
  const int bid = blockIdx.x;
  const int L   = (bid & 7) * 64 + (bid >> 3);
  const int i   = L >> 7;
  const int nt  = (L >> 3) & 15;
  const int bt  = L & 7;
  const int b0  = bt * 64;
  const int o0  = nt * 64;

  const int tid  = threadIdx.x;
  const int lane = tid & 63;
  const int wid  = tid >> 6;

  __shared__ __align__(16) char smem[34816];
  __bf16* Is = (__bf16*)smem;             // [64][128], 16 KB
  __bf16* Bs = (__bf16*)(smem + 16384);   // [64][128], 16 KB
  float*  red = (float*)smem;             // epilogue: [2][64][68] f32

  f32x4 acc[4][4];
#pragma unroll
  for (int a_ = 0; a_ < 4; ++a_)
#pragma unroll
    for (int b_ = 0; b_ < 4; ++b_)
      acc[a_][b_] = (f32x4){0.f, 0.f, 0.f, 0.f};

  const __bf16* ibase = inner + ((size_t)i * B_SZ + b0) * KTOT;
  const float*  Bbase = Bm + (size_t)i * KTOT * D_OUTD + o0;

  const int bo  = tid & 63;   // B-stage: column o
  const int bog = tid >> 6;   // 0..3 -> 4 k-octets each

  for (int kt = 0; kt < KTOT/128; ++kt) {
    // ---- inner -> Is via global_load_lds, source pre-swizzled ----
#pragma unroll
    for (int q = 0; q < 4; ++q) {
      const int ci  = wid*4 + q;                 // wave-uniform
      const int row = ci*4 + (lane >> 4);
      const int kch = (lane & 15) ^ (row & 15);
      gload_lds16(ibase + (size_t)row * KTOT + kt*128 + kch*8,
                  Is + ci*512);
    }
    // ---- B -> Bs_t transposed bf16 ----
#pragma unroll
    for (int q = 0; q < 4; ++q) {
      const int oct = bog*4 + q;                 // k-octet 0..15
      float v[8];
#pragma unroll
      for (int j = 0; j < 8; ++j)
        v[j] = Bbase[(size_t)(kt*128 + oct*8 + j)*D_OUTD + bo]; // 256B coalesced
      bf16x8 h;
#pragma unroll
      for (int j = 0; j < 8; ++j) h[j] = (__bf16)v[j];
      *(bf16x8*)(Bs + bo*128 + ((oct ^ (bo & 15)))*8) = h;
    }
    __syncthreads();

    // ---- compute: wave wid covers k-octets wid*4 + (lane>>4) ----
    {
      const int oct = wid*4 + (lane >> 4);
      bf16x8 af[4];
#pragma unroll
      for (int mi = 0; mi < 4; ++mi) {
        const int row = mi*16 + (lane & 15);
        af[mi] = *(const bf16x8*)(Is + row*128 + ((oct ^ (row & 15)))*8);
      }
#pragma unroll
      for (int ni = 0; ni < 4; ++ni) {
        const int col = ni*16 + (lane & 15);
        bf16x8 bfr = *(const bf16x8*)(Bs + col*128 + ((oct ^ (col & 15)))*8);
#pragma unroll
        for (int mi = 0; mi < 4; ++mi)
          acc[mi][ni] = __builtin_amdgcn_mfma_f32_16x16x32_bf16(af[mi], bfr, acc[mi][ni], 0, 0, 0);
      }
    }
    __syncthreads();
  }

  // ---- cross-wave K reduction via LDS ([col][row], pad 68 -> 2-way max) ----
  const int rr0 = (lane >> 4) * 4;
  if (wid >= 2) {
#pragma unroll
    for (int mi = 0; mi < 4; ++mi)
#pragma unroll
      for (int ni = 0; ni < 4; ++ni) {
        const int col = ni*16 + (lane & 15);
        *(f32x4*)(red + (wid-2)*4352 + col*68 + mi*16 + rr0) = acc[mi][ni];
      }
  }
  __syncthreads();
  if (wid < 2) {
#pragma unroll
    for (int mi = 0; mi < 4; ++mi)
#pragma unroll
      for (int ni = 0; ni < 4; ++ni) {
        const int col = ni*16 + (lane & 15);
        acc[mi][ni] += *(const f32x4*)(red + wid*4352 + col*68 + mi*16 + rr0);
      }
  }
  __syncthreads();
  if (wid == 1) {
#pragma unroll
    for (int mi = 0; mi < 4; ++mi)
#pragma unroll
      for (int ni = 0; ni < 4; ++ni) {
        const int col = ni*16 + (lane & 15);
        *(f32x4*)(red + col*68 + mi*16 + rr0) = acc[mi][ni];
      }
  }
  __syncthreads();
  if (wid == 0) {
#pragma unroll
    for (int mi = 0; mi < 4; ++mi)
#pragma unroll
      for (int ni = 0; ni < 4; ++ni) {
        const int col = ni*16 + (lane & 15);
        acc[mi][ni] += *(const f32x4*)(red + col*68 + mi*16 + rr0);
      }
    float* obase = out + ((size_t)b0 * NINST + i) * D_OUTD + o0;
#pragma unroll
    for (int mi = 0; mi < 4; ++mi)
#pragma unroll
      for (int ni = 0; ni < 4; ++ni) {
        const int colL = ni*16 + (lane & 15);
#pragma unroll
        for (int j = 0; j < 4; ++j) {
          const int rowL = mi*16 + rr0 + j;
          obase[(size_t)rowL * (NINST*D_OUTD) + colL] = acc[mi][ni][j];
        }
      }
  }
}

extern "C" void kernel_launch(void* const* d_in, const int* in_sizes, int n_in,
                              void* d_out, int out_size, void* d_ws, size_t ws_size,
                              hipStream_t stream) {
  const float* x    = (const float*)d_in[0];
  const float* A    = (const float*)d_in[1];
  const float* Bm   = (const float*)d_in[2];
  const int*   mask = (const int*)d_in[3];
  __bf16* inner = (__bf16*)d_ws;   // 64 MB

  p1_kernel<<<dim3(NINST*CCOMP*8), dim3(256), 0, stream>>>(x, A, mask, inner);
  p2_kernel<<<dim3(512),           dim3(256), 0, stream>>>(inner, Bm, (float*)d_out);
}

// Round 3
// 364.636 us; speedup vs baseline: 1.5860x; 1.4434x over previous
//
#include <hip/hip_runtime.h>
#include <hip/hip_bf16.h>
#include <stdint.h>

#define B_SZ   512
#define NINST  4
#define D_IN   1024
#define D_OUTD 1024
#define CCOMP  64
#define MRANK  256
#define KTOT   (CCOMP*MRANK)   // 16384

typedef __attribute__((ext_vector_type(4))) float  f32x4;
typedef __attribute__((ext_vector_type(8))) __bf16 bf16x8;
typedef __attribute__((ext_vector_type(4))) __bf16 bf16x4;

__device__ inline void gload_lds16(const __bf16* g, __bf16* l) {
  __builtin_amdgcn_global_load_lds(
      (const __attribute__((address_space(1))) void*)g,
      (__attribute__((address_space(3))) void*)l, 16, 0, 0);
}

// ---------------------------------------------------------------------------
// Phase 1: inner[i][b][c*256+m] = mask[b][i][c] * sum_d x[b][i][d]*A[i][c][d][m]
// 2048 blocks (XCD-swizzled), 512 thr = 8 waves (2 x 4), tile 128b x 128m,
// BK=64, 16 K-steps. T14 pipeline: loads(t+1)->regs issued before compute(t),
// double-buffered LDS, ONE barrier per step.
// Xs: [2][128][64] XOR-chunk swizzled. As_t: [2][128][72] m-major, +8 pad
// (stride 144B: bank-spread on both write and b128 read, no XOR needed).
// ---------------------------------------------------------------------------
__global__ __launch_bounds__(512, 2)
void p1_kernel(const float* __restrict__ x, const float* __restrict__ A,
               const int* __restrict__ mask, __bf16* __restrict__ inner)
{
  const int bid = blockIdx.x;
  const int L   = (bid & 7) * 256 + (bid >> 3);
  const int ic  = L >> 3;
  const int i   = ic >> 6;
  const int c   = ic & 63;
  const int bt  = (L >> 1) & 3;
  const int nt  = L & 1;
  const int b0  = bt * 128;
  const int m0  = nt * 128;

  const int tid  = threadIdx.x;
  const int lane = tid & 63;
  const int wid  = tid >> 6;     // 0..7
  const int wr   = wid >> 2;     // 0..1 : 64-row strip
  const int wc   = wid & 3;      // 0..3 : 32-col strip

  __shared__ __bf16 Xs[2][128][64];    // 32 KB
  __shared__ __bf16 As_t[2][128][72];  // 36 KB, padded
  __shared__ int    Msk[128];

  if (tid < 128)
    Msk[tid] = mask[(size_t)(b0 + tid) * (NINST*CCOMP) + i*CCOMP + c];

  f32x4 acc[4][2];
#pragma unroll
  for (int a_ = 0; a_ < 4; ++a_)
#pragma unroll
    for (int b_ = 0; b_ < 2; ++b_)
      acc[a_][b_] = (f32x4){0.f, 0.f, 0.f, 0.f};

  const float* xbase = x + ((size_t)b0 * NINST + i) * D_IN;
  const float* Abase = A + (size_t)ic * D_IN * MRANK + m0;

  // staging geometry
  const int xr = tid >> 4;       // 0..31
  const int kc = tid & 15;
  const int am = tid & 127;
  const int og = tid >> 7;       // 0..3 -> octets {2og, 2og+1}

  f32x4 xreg[4];
  float areg[2][8];

  auto loadX = [&](int kt) {
#pragma unroll
    for (int rr = 0; rr < 4; ++rr)
      xreg[rr] = *(const f32x4*)(xbase + (size_t)(xr + rr*32)*(NINST*D_IN) + kt*64 + kc*4);
  };
  auto loadA = [&](int kt) {
#pragma unroll
    for (int q = 0; q < 2; ++q)
#pragma unroll
      for (int j = 0; j < 8; ++j)
        areg[q][j] = Abase[(size_t)(kt*64 + (og*2+q)*8 + j)*MRANK + am];
  };
  auto writeX = [&](int buf) {
#pragma unroll
    for (int rr = 0; rr < 4; ++rr) {
      const int row = xr + rr*32;
      bf16x4 h; h[0]=(__bf16)xreg[rr].x; h[1]=(__bf16)xreg[rr].y;
                h[2]=(__bf16)xreg[rr].z; h[3]=(__bf16)xreg[rr].w;
      const int chunk = (kc >> 1) ^ (row & 7);
      *(bf16x4*)(&Xs[buf][row][chunk*8 + (kc & 1)*4]) = h;
    }
  };
  auto writeA = [&](int buf) {
#pragma unroll
    for (int q = 0; q < 2; ++q) {
      bf16x8 h;
#pragma unroll
      for (int j = 0; j < 8; ++j) h[j] = (__bf16)areg[q][j];
      *(bf16x8*)(&As_t[buf][am][(og*2+q)*8]) = h;
    }
  };

  loadX(0); loadA(0); writeX(0); writeA(0);
  __syncthreads();

  int cur = 0;
  for (int kt = 0; kt < 16; ++kt) {
    if (kt < 15) { loadX(kt+1); loadA(kt+1); }   // in flight during compute
#pragma unroll
    for (int kk = 0; kk < 2; ++kk) {
      bf16x8 af[4];
#pragma unroll
      for (int mi = 0; mi < 4; ++mi) {
        const int row = wr*64 + mi*16 + (lane & 15);
        const int chunk = (kk*4 + (lane >> 4)) ^ (row & 7);
        af[mi] = *(const bf16x8*)(&Xs[cur][row][chunk*8]);
      }
#pragma unroll
      for (int ni = 0; ni < 2; ++ni) {
        const int col = wc*32 + ni*16 + (lane & 15);
        bf16x8 bfr = *(const bf16x8*)(&As_t[cur][col][(kk*4 + (lane >> 4))*8]);
#pragma unroll
        for (int mi = 0; mi < 4; ++mi)
          acc[mi][ni] = __builtin_amdgcn_mfma_f32_16x16x32_bf16(af[mi], bfr, acc[mi][ni], 0, 0, 0);
      }
    }
    if (kt < 15) { writeX(cur ^ 1); writeA(cur ^ 1); }  // waits loads here
    __syncthreads();
    cur ^= 1;
  }

  __bf16* obase = inner + ((size_t)i * B_SZ + b0) * KTOT + (size_t)c * MRANK + m0;
#pragma unroll
  for (int mi = 0; mi < 4; ++mi)
#pragma unroll
    for (int ni = 0; ni < 2; ++ni) {
      const int colL = wc*32 + ni*16 + (lane & 15);
#pragma unroll
      for (int j = 0; j < 4; ++j) {
        const int rowL = wr*64 + mi*16 + (lane >> 4)*4 + j;
        const float mval = (float)Msk[rowL];
        obase[(size_t)rowL * KTOT + colL] = (__bf16)(acc[mi][ni][j] * mval);
      }
    }
}

// ---------------------------------------------------------------------------
// Phase 2: out[b][i][o] = sum_K inner[i][b][K] * Bflat[i][K][o],  K = 16384
// K-split across nks block groups (partials in ws, reduced after), 512*nks
// blocks XCD-swizzled. 256 thr = 4 waves, tile 64b x 64o, BK=128, wave-K-split
// (wave w owns k-octets w*4..w*4+3; cross-wave LDS reduce at end).
// Pipeline: Is double-buffered via global_load_lds (pre-swizzled source),
// Bs single-buffered [64][136] padded, T14 reg staging; 2 barriers/step.
// ---------------------------------------------------------------------------
__global__ __launch_bounds__(256, 3)
void p2_kernel(const __bf16* __restrict__ inner, const float* __restrict__ Bm,
               float* __restrict__ dst, int nks)
{
  const int bid = blockIdx.x;
  const int swz = (bid & 7) * (gridDim.x >> 3) + (bid >> 3);
  const int ks   = swz % nks;
  const int rest = swz / nks;
  const int bt  = rest & 7;
  const int nt  = (rest >> 3) & 15;
  const int i   = rest >> 7;
  const int b0  = bt * 64;
  const int o0  = nt * 64;
  const int NSTEP = (KTOT/128) / nks;
  const int kb0   = ks * NSTEP;

  const int tid  = threadIdx.x;
  const int lane = tid & 63;
  const int wid  = tid >> 6;

  __shared__ __align__(16) char smem[2*16384 + 64*136*2];  // 50176 B
  __bf16* Is = (__bf16*)smem;                 // [2][64][128]
  __bf16* Bs = (__bf16*)(smem + 32768);       // [64][136] padded
  float*  red = (float*)smem;                 // epilogue overlay [2][64][68]

  f32x4 acc[4][4];
#pragma unroll
  for (int a_ = 0; a_ < 4; ++a_)
#pragma unroll
    for (int b_ = 0; b_ < 4; ++b_)
      acc[a_][b_] = (f32x4){0.f, 0.f, 0.f, 0.f};

  const __bf16* ibase = inner + ((size_t)i * B_SZ + b0) * KTOT;
  const float*  Bbase = Bm + (size_t)i * KTOT * D_OUTD + o0;

  const int bo  = tid & 63;
  const int bog = tid >> 6;

  float breg[4][8];

  auto stageIs = [&](int buf, int kt) {
#pragma unroll
    for (int q = 0; q < 4; ++q) {
      const int ci  = wid*4 + q;                 // wave-uniform
      const int row = ci*4 + (lane >> 4);
      const int kch = (lane & 15) ^ (row & 15);  // pre-swizzled source
      gload_lds16(ibase + (size_t)row * KTOT + kt*128 + kch*8,
                  Is + buf*8192 + ci*512);
    }
  };
  auto loadB = [&](int kt) {
#pragma unroll
    for (int q = 0; q < 4; ++q)
#pragma unroll
      for (int j = 0; j < 8; ++j)
        breg[q][j] = Bbase[(size_t)(kt*128 + (bog*4+q)*8 + j)*D_OUTD + bo];
  };
  auto writeB = [&]() {
#pragma unroll
    for (int q = 0; q < 4; ++q) {
      bf16x8 h;
#pragma unroll
      for (int j = 0; j < 8; ++j) h[j] = (__bf16)breg[q][j];
      *(bf16x8*)(Bs + bo*136 + (bog*4+q)*8) = h;
    }
  };

  stageIs(0, kb0); loadB(kb0); writeB();
  __syncthreads();                               // drains Is DMA too

  int cur = 0;
  for (int t = 0; t < NSTEP; ++t) {
    if (t+1 < NSTEP) { stageIs(cur ^ 1, kb0 + t + 1); loadB(kb0 + t + 1); }
    {
      const int oct = wid*4 + (lane >> 4);
      bf16x8 af[4];
#pragma unroll
      for (int mi = 0; mi < 4; ++mi) {
        const int row = mi*16 + (lane & 15);
        af[mi] = *(const bf16x8*)(Is + cur*8192 + row*128 + ((oct ^ (row & 15)))*8);
      }
#pragma unroll
      for (int ni = 0; ni < 4; ++ni) {
        const int col = ni*16 + (lane & 15);
        bf16x8 bfr = *(const bf16x8*)(Bs + col*136 + oct*8);
#pragma unroll
        for (int mi = 0; mi < 4; ++mi)
          acc[mi][ni] = __builtin_amdgcn_mfma_f32_16x16x32_bf16(af[mi], bfr, acc[mi][ni], 0, 0, 0);
      }
    }
    __syncthreads();                 // all Bs reads done; drains t+1 loads/DMA
    if (t+1 < NSTEP) writeB();
    __syncthreads();
    cur ^= 1;
  }

  // ---- cross-wave K reduction via LDS ----
  const int rr0 = (lane >> 4) * 4;
  if (wid >= 2) {
#pragma unroll
    for (int mi = 0; mi < 4; ++mi)
#pragma unroll
      for (int ni = 0; ni < 4; ++ni) {
        const int col = ni*16 + (lane & 15);
        *(f32x4*)(red + (wid-2)*4352 + col*68 + mi*16 + rr0) = acc[mi][ni];
      }
  }
  __syncthreads();
  if (wid < 2) {
#pragma unroll
    for (int mi = 0; mi < 4; ++mi)
#pragma unroll
      for (int ni = 0; ni < 4; ++ni) {
        const int col = ni*16 + (lane & 15);
        acc[mi][ni] += *(const f32x4*)(red + wid*4352 + col*68 + mi*16 + rr0);
      }
  }
  __syncthreads();
  if (wid == 1) {
#pragma unroll
    for (int mi = 0; mi < 4; ++mi)
#pragma unroll
      for (int ni = 0; ni < 4; ++ni) {
        const int col = ni*16 + (lane & 15);
        *(f32x4*)(red + col*68 + mi*16 + rr0) = acc[mi][ni];
      }
  }
  __syncthreads();
  if (wid == 0) {
#pragma unroll
    for (int mi = 0; mi < 4; ++mi)
#pragma unroll
      for (int ni = 0; ni < 4; ++ni) {
        const int col = ni*16 + (lane & 15);
        acc[mi][ni] += *(const f32x4*)(red + col*68 + mi*16 + rr0);
      }
    float* obase = dst + (size_t)ks * ((size_t)B_SZ*NINST*D_OUTD)
                 + ((size_t)b0 * NINST + i) * D_OUTD + o0;
#pragma unroll
    for (int mi = 0; mi < 4; ++mi)
#pragma unroll
      for (int ni = 0; ni < 4; ++ni) {
        const int colL = ni*16 + (lane & 15);
#pragma unroll
        for (int j = 0; j < 4; ++j) {
          const int rowL = mi*16 + rr0 + j;
          obase[(size_t)rowL * (NINST*D_OUTD) + colL] = acc[mi][ni][j];
        }
      }
  }
}

// ---------------------------------------------------------------------------
// Reduce nks partials -> out.  8.4 MB out, ~40 MB traffic, ~8 us.
// ---------------------------------------------------------------------------
__global__ __launch_bounds__(256)
void reduce_kernel(const float* __restrict__ part, float* __restrict__ out, int nks)
{
  const int total = (B_SZ*NINST*D_OUTD) / 4;     // f32x4 count
  for (int v = blockIdx.x*256 + threadIdx.x; v < total; v += gridDim.x*256) {
    f32x4 s = ((const f32x4*)part)[v];
    for (int ks = 1; ks < nks; ++ks)
      s += ((const f32x4*)part)[(size_t)ks*total + v];
    ((f32x4*)out)[v] = s;
  }
}

extern "C" void kernel_launch(void* const* d_in, const int* in_sizes, int n_in,
                              void* d_out, int out_size, void* d_ws, size_t ws_size,
                              hipStream_t stream) {
  const float* x    = (const float*)d_in[0];
  const float* A    = (const float*)d_in[1];
  const float* Bm   = (const float*)d_in[2];
  const int*   mask = (const int*)d_in[3];
  __bf16* inner = (__bf16*)d_ws;                              // 64 MB
  const size_t innerB = (size_t)NINST * B_SZ * KTOT * 2;
  const size_t partB  = (size_t)B_SZ * NINST * D_OUTD * 4;    // 8 MB per split

  const int nks = (ws_size >= innerB + 4*partB) ? 4 : 1;
  float* part = (nks > 1) ? (float*)((char*)d_ws + innerB) : (float*)d_out;

  p1_kernel<<<dim3(NINST*CCOMP*8), dim3(512), 0, stream>>>(x, A, mask, inner);
  p2_kernel<<<dim3(512*nks),       dim3(256), 0, stream>>>(inner, Bm, part, nks);
  if (nks > 1)
    reduce_kernel<<<dim3(1024), dim3(256), 0, stream>>>(part, (float*)d_out, nks);
}

// Round 4
// 319.090 us; speedup vs baseline: 1.8124x; 1.1427x over previous
//
#include <hip/hip_runtime.h>
#include <hip/hip_bf16.h>
#include <stdint.h>

#define B_SZ   512
#define NINST  4
#define D_IN   1024
#define D_OUTD 1024
#define CCOMP  64
#define MRANK  256
#define KTOT   (CCOMP*MRANK)   // 16384

typedef __attribute__((ext_vector_type(4))) float  f32x4;
typedef __attribute__((ext_vector_type(8))) __bf16 bf16x8;
typedef __attribute__((ext_vector_type(4))) __bf16 bf16x4;

__device__ inline void gload_lds16(const __bf16* g, __bf16* l) {
  __builtin_amdgcn_global_load_lds(
      (const __attribute__((address_space(1))) void*)g,
      (__attribute__((address_space(3))) void*)l, 16, 0, 0);
}

// ---------------------------------------------------------------------------
// Unified template: tile 128(M) x 256(N), BK=64, 512 thr = 8 waves (2x4),
// wave tile 64x64 (16 f32x4 acc), mfma 16x16x32 bf16.
// LDS: Ms [2][128][64] (M-operand, XOR-chunk swizzle, R2-verified),
//      Ns [2][256][64] (N-operand transposed n-major, XOR swizzle).
// Pipeline: issue loads(t+1) -> compute(t) -> cvt+write(t+1) -> barrier.
// ---------------------------------------------------------------------------

// Phase 1: inner[i][b][c*256+m] = mask * (x . A).  M=b(128 of 512), N=m(256),
// K=d(1024). grid 1024 = 4bt x 256ic, XCD-swizzled (bt-sharers of A adjacent).
__global__ __launch_bounds__(512, 2)
void p1_kernel(const float* __restrict__ x, const float* __restrict__ A,
               const int* __restrict__ mask, __bf16* __restrict__ inner)
{
  const int bid = blockIdx.x;
  const int L   = (bid & 7) * 128 + (bid >> 3);
  const int ic  = L >> 2;          // i*64 + c
  const int i   = ic >> 6;
  const int c   = ic & 63;
  const int b0  = (L & 3) * 128;

  const int tid  = threadIdx.x;
  const int lane = tid & 63;
  const int wid  = tid >> 6;       // 0..7
  const int wr   = wid >> 2;       // 0..1 : 64-row strip
  const int wc   = wid & 3;        // 0..3 : 64-col strip

  __shared__ __bf16 Xs[2][128][64];
  __shared__ __bf16 As[2][256][64];
  __shared__ int    Msk[128];

  if (tid < 128)
    Msk[tid] = mask[(size_t)(b0 + tid) * (NINST*CCOMP) + i*CCOMP + c];

  f32x4 acc[4][4];
#pragma unroll
  for (int a_ = 0; a_ < 4; ++a_)
#pragma unroll
    for (int b_ = 0; b_ < 4; ++b_)
      acc[a_][b_] = (f32x4){0.f, 0.f, 0.f, 0.f};

  const float* xbase = x + ((size_t)b0 * NINST + i) * D_IN;
  const float* Abase = A + (size_t)ic * D_IN * MRANK;

  // staging geometry
  const int xr = tid >> 4;         // 0..31 (rows, +32 stride)
  const int kc = tid & 15;         // f32x4 index in row
  const int am = tid & 255;        // A column m
  const int ag = tid >> 8;         // 0..1 -> 4 k-octets each

  f32x4 xreg[4];
  float areg[4][8];

  auto loadX = [&](int kt) {
#pragma unroll
    for (int rr = 0; rr < 4; ++rr)
      xreg[rr] = *(const f32x4*)(xbase + (size_t)(xr + rr*32)*(NINST*D_IN) + kt*64 + kc*4);
  };
  auto loadA = [&](int kt) {
#pragma unroll
    for (int q = 0; q < 4; ++q)
#pragma unroll
      for (int j = 0; j < 8; ++j)
        areg[q][j] = Abase[(size_t)(kt*64 + (ag*4+q)*8 + j)*MRANK + am];
  };
  auto writeX = [&](int buf) {
#pragma unroll
    for (int rr = 0; rr < 4; ++rr) {
      const int row = xr + rr*32;
      bf16x4 h; h[0]=(__bf16)xreg[rr].x; h[1]=(__bf16)xreg[rr].y;
                h[2]=(__bf16)xreg[rr].z; h[3]=(__bf16)xreg[rr].w;
      const int chunk = (kc >> 1) ^ (row & 7);
      *(bf16x4*)(&Xs[buf][row][chunk*8 + (kc & 1)*4]) = h;
    }
  };
  auto writeA = [&](int buf) {
#pragma unroll
    for (int q = 0; q < 4; ++q) {
      bf16x8 h;
#pragma unroll
      for (int j = 0; j < 8; ++j) h[j] = (__bf16)areg[q][j];
      *(bf16x8*)(&As[buf][am][(((ag*4+q) ^ (am & 7)))*8]) = h;
    }
  };

  loadX(0); loadA(0); writeX(0); writeA(0);
  __syncthreads();

  int cur = 0;
  for (int kt = 0; kt < D_IN/64; ++kt) {
    if (kt+1 < D_IN/64) { loadX(kt+1); loadA(kt+1); }
#pragma unroll
    for (int kk = 0; kk < 2; ++kk) {
      const int oct = kk*4 + (lane >> 4);
      bf16x8 af[4];
#pragma unroll
      for (int mi = 0; mi < 4; ++mi) {
        const int row = wr*64 + mi*16 + (lane & 15);
        af[mi] = *(const bf16x8*)(&Xs[cur][row][((oct ^ (row & 7)))*8]);
      }
#pragma unroll
      for (int ni = 0; ni < 4; ++ni) {
        const int col = wc*64 + ni*16 + (lane & 15);
        bf16x8 bfr = *(const bf16x8*)(&As[cur][col][((oct ^ (col & 7)))*8]);
#pragma unroll
        for (int mi = 0; mi < 4; ++mi)
          acc[mi][ni] = __builtin_amdgcn_mfma_f32_16x16x32_bf16(af[mi], bfr, acc[mi][ni], 0, 0, 0);
      }
    }
    if (kt+1 < D_IN/64) { writeX(cur ^ 1); writeA(cur ^ 1); }
    __syncthreads();
    cur ^= 1;
  }

  __bf16* obase = inner + ((size_t)i * B_SZ + b0) * KTOT + (size_t)c * MRANK;
#pragma unroll
  for (int mi = 0; mi < 4; ++mi)
#pragma unroll
    for (int ni = 0; ni < 4; ++ni) {
      const int colL = wc*64 + ni*16 + (lane & 15);
#pragma unroll
      for (int j = 0; j < 4; ++j) {
        const int rowL = wr*64 + mi*16 + (lane >> 4)*4 + j;
        const float mval = (float)Msk[rowL];
        obase[(size_t)rowL * KTOT + colL] = (__bf16)(acc[mi][ni][j] * mval);
      }
    }
}

// Phase 2: part[ks][b][i][o] = sum_{K slice} inner[i][b][K] * Bflat[i][K][o].
// M=b(128 of 512), N=o(256 of 1024), K-slice = 16384/nks. grid 64*nks,
// XCD-swizzled, order (i,ks) -> nt -> bt so B's bt-sharers are adjacent.
__global__ __launch_bounds__(512, 2)
void p2_kernel(const __bf16* __restrict__ inner, const float* __restrict__ Bm,
               float* __restrict__ dst, int nks)
{
  const int bid = blockIdx.x;
  const int L   = (bid & 7) * (gridDim.x >> 3) + (bid >> 3);
  const int bt  = L & 3;
  const int nt  = (L >> 2) & 3;
  const int rest = L >> 4;         // i*nks + ks
  const int ks  = rest % nks;
  const int i   = rest / nks;
  const int b0  = bt * 128;
  const int o0  = nt * 256;
  const int NSTEP = (KTOT/64) / nks;
  const int kb0   = ks * NSTEP;

  const int tid  = threadIdx.x;
  const int lane = tid & 63;
  const int wid  = tid >> 6;
  const int wr   = wid >> 2;
  const int wc   = wid & 3;

  __shared__ __bf16 Is[2][128][64];
  __shared__ __bf16 Bs[2][256][64];

  f32x4 acc[4][4];
#pragma unroll
  for (int a_ = 0; a_ < 4; ++a_)
#pragma unroll
    for (int b_ = 0; b_ < 4; ++b_)
      acc[a_][b_] = (f32x4){0.f, 0.f, 0.f, 0.f};

  const __bf16* ibase = inner + ((size_t)i * B_SZ + b0) * KTOT;
  const float*  Bbase = Bm + (size_t)i * KTOT * D_OUTD + o0;

  const int bo = tid & 255;        // B column o
  const int bg = tid >> 8;         // 0..1 -> 4 k-octets each

  float breg[4][8];

  auto stageIs = [&](int buf, int kt) {
#pragma unroll
    for (int q = 0; q < 2; ++q) {
      const int ci  = wid*2 + q;                 // 0..15, wave-uniform
      const int row = ci*8 + (lane >> 3);
      const int kch = (lane & 7) ^ (row & 7);    // pre-swizzled source
      gload_lds16(ibase + (size_t)row * KTOT + kt*64 + kch*8,
                  &Is[0][0][0] + buf*8192 + ci*512);
    }
  };
  auto loadB = [&](int kt) {
#pragma unroll
    for (int q = 0; q < 4; ++q)
#pragma unroll
      for (int j = 0; j < 8; ++j)
        breg[q][j] = Bbase[(size_t)(kt*64 + (bg*4+q)*8 + j)*D_OUTD + bo];
  };
  auto writeB = [&](int buf) {
#pragma unroll
    for (int q = 0; q < 4; ++q) {
      bf16x8 h;
#pragma unroll
      for (int j = 0; j < 8; ++j) h[j] = (__bf16)breg[q][j];
      *(bf16x8*)(&Bs[buf][bo][(((bg*4+q) ^ (bo & 7)))*8]) = h;
    }
  };

  stageIs(0, kb0); loadB(kb0); writeB(0);
  __syncthreads();

  int cur = 0;
  for (int t = 0; t < NSTEP; ++t) {
    if (t+1 < NSTEP) { stageIs(cur ^ 1, kb0 + t + 1); loadB(kb0 + t + 1); }
#pragma unroll
    for (int kk = 0; kk < 2; ++kk) {
      const int oct = kk*4 + (lane >> 4);
      bf16x8 af[4];
#pragma unroll
      for (int mi = 0; mi < 4; ++mi) {
        const int row = wr*64 + mi*16 + (lane & 15);
        af[mi] = *(const bf16x8*)(&Is[cur][row][((oct ^ (row & 7)))*8]);
      }
#pragma unroll
      for (int ni = 0; ni < 4; ++ni) {
        const int col = wc*64 + ni*16 + (lane & 15);
        bf16x8 bfr = *(const bf16x8*)(&Bs[cur][col][((oct ^ (col & 7)))*8]);
#pragma unroll
        for (int mi = 0; mi < 4; ++mi)
          acc[mi][ni] = __builtin_amdgcn_mfma_f32_16x16x32_bf16(af[mi], bfr, acc[mi][ni], 0, 0, 0);
      }
    }
    if (t+1 < NSTEP) writeB(cur ^ 1);
    __syncthreads();
    cur ^= 1;
  }

  float* obase = dst + (size_t)ks * ((size_t)B_SZ*NINST*D_OUTD)
               + ((size_t)b0 * NINST + i) * D_OUTD + o0;
#pragma unroll
  for (int mi = 0; mi < 4; ++mi)
#pragma unroll
    for (int ni = 0; ni < 4; ++ni) {
      const int colL = wc*64 + ni*16 + (lane & 15);
#pragma unroll
      for (int j = 0; j < 4; ++j) {
        const int rowL = wr*64 + mi*16 + (lane >> 4)*4 + j;
        obase[(size_t)rowL * (NINST*D_OUTD) + colL] = acc[mi][ni][j];
      }
    }
}

__global__ __launch_bounds__(256)
void reduce_kernel(const float* __restrict__ part, float* __restrict__ out, int nks)
{
  const int total = (B_SZ*NINST*D_OUTD) / 4;
  for (int v = blockIdx.x*256 + threadIdx.x; v < total; v += gridDim.x*256) {
    f32x4 s = ((const f32x4*)part)[v];
    for (int ks = 1; ks < nks; ++ks)
      s += ((const f32x4*)part)[(size_t)ks*total + v];
    ((f32x4*)out)[v] = s;
  }
}

extern "C" void kernel_launch(void* const* d_in, const int* in_sizes, int n_in,
                              void* d_out, int out_size, void* d_ws, size_t ws_size,
                              hipStream_t stream) {
  const float* x    = (const float*)d_in[0];
  const float* A    = (const float*)d_in[1];
  const float* Bm   = (const float*)d_in[2];
  const int*   mask = (const int*)d_in[3];
  __bf16* inner = (__bf16*)d_ws;                              // 64 MB
  const size_t innerB = (size_t)NINST * B_SZ * KTOT * 2;
  const size_t partB  = (size_t)B_SZ * NINST * D_OUTD * 4;    // 8 MB per split

  int nks = 1;
  if      (ws_size >= innerB + 4*partB) nks = 4;
  else if (ws_size >= innerB + 2*partB) nks = 2;
  float* part = (nks > 1) ? (float*)((char*)d_ws + innerB) : (float*)d_out;

  p1_kernel<<<dim3(1024),   dim3(512), 0, stream>>>(x, A, mask, inner);
  p2_kernel<<<dim3(64*nks), dim3(512), 0, stream>>>(inner, Bm, part, nks);
  if (nks > 1)
    reduce_kernel<<<dim3(512), dim3(256), 0, stream>>>(part, (float*)d_out, nks);
}

// Round 5
// 299.500 us; speedup vs baseline: 1.9309x; 1.0654x over previous
//
#include <hip/hip_runtime.h>
#include <hip/hip_bf16.h>
#include <stdint.h>

#define B_SZ   512
#define NINST  4
#define D_IN   1024
#define D_OUTD 1024
#define CCOMP  64
#define MRANK  256
#define KTOT   (CCOMP*MRANK)   // 16384

typedef __attribute__((ext_vector_type(4))) float  f32x4;
typedef __attribute__((ext_vector_type(8))) __bf16 bf16x8;
typedef __attribute__((ext_vector_type(4))) __bf16 bf16x4;

__device__ inline void gload_lds16(const __bf16* g, __bf16* l) {
  __builtin_amdgcn_global_load_lds(
      (const __attribute__((address_space(1))) void*)g,
      (__attribute__((address_space(3))) void*)l, 16, 0, 0);
}

// ---------------------------------------------------------------------------
// Prepass: xbf[i][b][k] = bf16(x[b][i][k]).  12 MB traffic, ~3 us.
// Makes p1's M-operand k-contig bf16 so it can be staged via global_load_lds.
// ---------------------------------------------------------------------------
__global__ __launch_bounds__(256)
void xcvt_kernel(const float* __restrict__ x, __bf16* __restrict__ xbf)
{
  const int total = (B_SZ*NINST*D_IN) / 4;     // f32x4 count
  for (int v = blockIdx.x*256 + threadIdx.x; v < total; v += gridDim.x*256) {
    const int k4 = v & 255;          // 1024/4
    const int i  = (v >> 8) & 3;
    const int b  = v >> 10;
    f32x4 f = ((const f32x4*)x)[v];
    bf16x4 h; h[0]=(__bf16)f.x; h[1]=(__bf16)f.y; h[2]=(__bf16)f.z; h[3]=(__bf16)f.w;
    ((bf16x4*)xbf)[((size_t)i*B_SZ + b)*256 + k4] = h;
  }
}

// ---------------------------------------------------------------------------
// Unified GEMM template (structure-parity p1/p2): tile 128(M) x 256(N), BK=64,
// 512 thr = 8 waves (2x4), wave tile 64x64, mfma 16x16x32 bf16.
// M-operand: global_load_lds DMA, source pre-XOR-swizzled (m173 pattern).
// N-operand: 32 scalar dword loads/thread (transposed), cvt->bf16, b128 writes
// into n-major XOR-swizzled LDS (all patterns measured conflict-free).
// Pipeline: issue(t+1) -> compute(t) -> writeN(t+1) -> ONE barrier.
// ---------------------------------------------------------------------------

// Phase 1: inner[i][b][c*256+m] = mask * (xbf . A).  grid 1024 (4 rounds/CU).
__global__ __launch_bounds__(512, 2)
void p1_kernel(const __bf16* __restrict__ xbf, const float* __restrict__ A,
               const int* __restrict__ mask, __bf16* __restrict__ inner)
{
  const int bid = blockIdx.x;
  const int L   = (bid & 7) * 128 + (bid >> 3);
  const int ic  = L >> 2;          // i*64 + c
  const int i   = ic >> 6;
  const int c   = ic & 63;
  const int b0  = (L & 3) * 128;

  const int tid  = threadIdx.x;
  const int lane = tid & 63;
  const int wid  = tid >> 6;       // 0..7
  const int wr   = wid >> 2;       // 0..1 : 64-row strip
  const int wc   = wid & 3;        // 0..3 : 64-col strip

  __shared__ __bf16 Xs[2][128][64];
  __shared__ __bf16 As[2][256][64];
  __shared__ int    Msk[128];

  if (tid < 128)
    Msk[tid] = mask[(size_t)(b0 + tid) * (NINST*CCOMP) + i*CCOMP + c];

  f32x4 acc[4][4];
#pragma unroll
  for (int a_ = 0; a_ < 4; ++a_)
#pragma unroll
    for (int b_ = 0; b_ < 4; ++b_)
      acc[a_][b_] = (f32x4){0.f, 0.f, 0.f, 0.f};

  const __bf16* xbase = xbf + ((size_t)i * B_SZ + b0) * D_IN;
  const float*  Abase = A + (size_t)ic * D_IN * MRANK;

  const int am = tid & 255;        // A column m
  const int ag = tid >> 8;         // 0..1 -> 4 k-octets each

  float areg[4][8];

  auto stageXs = [&](int buf, int kt) {
#pragma unroll
    for (int q = 0; q < 2; ++q) {
      const int ci  = wid*2 + q;                 // 0..15, wave-uniform
      const int row = ci*8 + (lane >> 3);
      const int kch = (lane & 7) ^ (row & 7);    // pre-swizzled source
      gload_lds16(xbase + (size_t)row * D_IN + kt*64 + kch*8,
                  &Xs[0][0][0] + buf*8192 + ci*512);
    }
  };
  auto loadA = [&](int kt) {
#pragma unroll
    for (int q = 0; q < 4; ++q)
#pragma unroll
      for (int j = 0; j < 8; ++j)
        areg[q][j] = Abase[(size_t)(kt*64 + (ag*4+q)*8 + j)*MRANK + am];
  };
  auto writeA = [&](int buf) {
#pragma unroll
    for (int q = 0; q < 4; ++q) {
      bf16x8 h;
#pragma unroll
      for (int j = 0; j < 8; ++j) h[j] = (__bf16)areg[q][j];
      *(bf16x8*)(&As[buf][am][(((ag*4+q) ^ (am & 7)))*8]) = h;
    }
  };

  stageXs(0, 0); loadA(0); writeA(0);
  __syncthreads();

  int cur = 0;
  for (int kt = 0; kt < D_IN/64; ++kt) {
    if (kt+1 < D_IN/64) { stageXs(cur ^ 1, kt+1); loadA(kt+1); }
#pragma unroll
    for (int kk = 0; kk < 2; ++kk) {
      const int oct = kk*4 + (lane >> 4);
      bf16x8 af[4];
#pragma unroll
      for (int mi = 0; mi < 4; ++mi) {
        const int row = wr*64 + mi*16 + (lane & 15);
        af[mi] = *(const bf16x8*)(&Xs[cur][row][((oct ^ (row & 7)))*8]);
      }
#pragma unroll
      for (int ni = 0; ni < 4; ++ni) {
        const int col = wc*64 + ni*16 + (lane & 15);
        bf16x8 bfr = *(const bf16x8*)(&As[cur][col][((oct ^ (col & 7)))*8]);
#pragma unroll
        for (int mi = 0; mi < 4; ++mi)
          acc[mi][ni] = __builtin_amdgcn_mfma_f32_16x16x32_bf16(af[mi], bfr, acc[mi][ni], 0, 0, 0);
      }
    }
    if (kt+1 < D_IN/64) writeA(cur ^ 1);
    __syncthreads();
    cur ^= 1;
  }

  __bf16* obase = inner + ((size_t)i * B_SZ + b0) * KTOT + (size_t)c * MRANK;
#pragma unroll
  for (int mi = 0; mi < 4; ++mi)
#pragma unroll
    for (int ni = 0; ni < 4; ++ni) {
      const int colL = wc*64 + ni*16 + (lane & 15);
#pragma unroll
      for (int j = 0; j < 4; ++j) {
        const int rowL = wr*64 + mi*16 + (lane >> 4)*4 + j;
        const float mval = (float)Msk[rowL];
        obase[(size_t)rowL * KTOT + colL] = (__bf16)(acc[mi][ni][j] * mval);
      }
    }
}

// Phase 2: part[ks][b][i][o] = sum_{K slice} inner[i][b][K] * Bflat[i][K][o].
// Unchanged from R4 (measured ~93 us, ~58% HBM).
__global__ __launch_bounds__(512, 2)
void p2_kernel(const __bf16* __restrict__ inner, const float* __restrict__ Bm,
               float* __restrict__ dst, int nks)
{
  const int bid = blockIdx.x;
  const int L   = (bid & 7) * (gridDim.x >> 3) + (bid >> 3);
  const int bt  = L & 3;
  const int nt  = (L >> 2) & 3;
  const int rest = L >> 4;         // i*nks + ks
  const int ks  = rest % nks;
  const int i   = rest / nks;
  const int b0  = bt * 128;
  const int o0  = nt * 256;
  const int NSTEP = (KTOT/64) / nks;
  const int kb0   = ks * NSTEP;

  const int tid  = threadIdx.x;
  const int lane = tid & 63;
  const int wid  = tid >> 6;
  const int wr   = wid >> 2;
  const int wc   = wid & 3;

  __shared__ __bf16 Is[2][128][64];
  __shared__ __bf16 Bs[2][256][64];

  f32x4 acc[4][4];
#pragma unroll
  for (int a_ = 0; a_ < 4; ++a_)
#pragma unroll
    for (int b_ = 0; b_ < 4; ++b_)
      acc[a_][b_] = (f32x4){0.f, 0.f, 0.f, 0.f};

  const __bf16* ibase = inner + ((size_t)i * B_SZ + b0) * KTOT;
  const float*  Bbase = Bm + (size_t)i * KTOT * D_OUTD + o0;

  const int bo = tid & 255;        // B column o
  const int bg = tid >> 8;         // 0..1 -> 4 k-octets each

  float breg[4][8];

  auto stageIs = [&](int buf, int kt) {
#pragma unroll
    for (int q = 0; q < 2; ++q) {
      const int ci  = wid*2 + q;                 // 0..15, wave-uniform
      const int row = ci*8 + (lane >> 3);
      const int kch = (lane & 7) ^ (row & 7);    // pre-swizzled source
      gload_lds16(ibase + (size_t)row * KTOT + kt*64 + kch*8,
                  &Is[0][0][0] + buf*8192 + ci*512);
    }
  };
  auto loadB = [&](int kt) {
#pragma unroll
    for (int q = 0; q < 4; ++q)
#pragma unroll
      for (int j = 0; j < 8; ++j)
        breg[q][j] = Bbase[(size_t)(kt*64 + (bg*4+q)*8 + j)*D_OUTD + bo];
  };
  auto writeB = [&](int buf) {
#pragma unroll
    for (int q = 0; q < 4; ++q) {
      bf16x8 h;
#pragma unroll
      for (int j = 0; j < 8; ++j) h[j] = (__bf16)breg[q][j];
      *(bf16x8*)(&Bs[buf][bo][(((bg*4+q) ^ (bo & 7)))*8]) = h;
    }
  };

  stageIs(0, kb0); loadB(kb0); writeB(0);
  __syncthreads();

  int cur = 0;
  for (int t = 0; t < NSTEP; ++t) {
    if (t+1 < NSTEP) { stageIs(cur ^ 1, kb0 + t + 1); loadB(kb0 + t + 1); }
#pragma unroll
    for (int kk = 0; kk < 2; ++kk) {
      const int oct = kk*4 + (lane >> 4);
      bf16x8 af[4];
#pragma unroll
      for (int mi = 0; mi < 4; ++mi) {
        const int row = wr*64 + mi*16 + (lane & 15);
        af[mi] = *(const bf16x8*)(&Is[cur][row][((oct ^ (row & 7)))*8]);
      }
#pragma unroll
      for (int ni = 0; ni < 4; ++ni) {
        const int col = wc*64 + ni*16 + (lane & 15);
        bf16x8 bfr = *(const bf16x8*)(&Bs[cur][col][((oct ^ (col & 7)))*8]);
#pragma unroll
        for (int mi = 0; mi < 4; ++mi)
          acc[mi][ni] = __builtin_amdgcn_mfma_f32_16x16x32_bf16(af[mi], bfr, acc[mi][ni], 0, 0, 0);
      }
    }
    if (t+1 < NSTEP) writeB(cur ^ 1);
    __syncthreads();
    cur ^= 1;
  }

  float* obase = dst + (size_t)ks * ((size_t)B_SZ*NINST*D_OUTD)
               + ((size_t)b0 * NINST + i) * D_OUTD + o0;
#pragma unroll
  for (int mi = 0; mi < 4; ++mi)
#pragma unroll
    for (int ni = 0; ni < 4; ++ni) {
      const int colL = wc*64 + ni*16 + (lane & 15);
#pragma unroll
      for (int j = 0; j < 4; ++j) {
        const int rowL = wr*64 + mi*16 + (lane >> 4)*4 + j;
        obase[(size_t)rowL * (NINST*D_OUTD) + colL] = acc[mi][ni][j];
      }
    }
}

__global__ __launch_bounds__(256)
void reduce_kernel(const float* __restrict__ part, float* __restrict__ out, int nks)
{
  const int total = (B_SZ*NINST*D_OUTD) / 4;
  for (int v = blockIdx.x*256 + threadIdx.x; v < total; v += gridDim.x*256) {
    f32x4 s = ((const f32x4*)part)[v];
    for (int ks = 1; ks < nks; ++ks)
      s += ((const f32x4*)part)[(size_t)ks*total + v];
    ((f32x4*)out)[v] = s;
  }
}

extern "C" void kernel_launch(void* const* d_in, const int* in_sizes, int n_in,
                              void* d_out, int out_size, void* d_ws, size_t ws_size,
                              hipStream_t stream) {
  const float* x    = (const float*)d_in[0];
  const float* A    = (const float*)d_in[1];
  const float* Bm   = (const float*)d_in[2];
  const int*   mask = (const int*)d_in[3];

  const size_t innerB = (size_t)NINST * B_SZ * KTOT * 2;       // 64 MB
  const size_t xbfB   = (size_t)NINST * B_SZ * D_IN * 2;       // 4 MB
  const size_t partB  = (size_t)B_SZ * NINST * D_OUTD * 4;     // 8 MB per split

  __bf16* inner = (__bf16*)d_ws;
  __bf16* xbf   = (__bf16*)((char*)d_ws + innerB);

  int nks = 1;
  if      (ws_size >= innerB + xbfB + 4*partB) nks = 4;
  else if (ws_size >= innerB + xbfB + 2*partB) nks = 2;
  float* part = (nks > 1) ? (float*)((char*)d_ws + innerB + xbfB) : (float*)d_out;

  xcvt_kernel<<<dim3(1024),  dim3(256), 0, stream>>>(x, xbf);
  p1_kernel<<<dim3(1024),    dim3(512), 0, stream>>>(xbf, A, mask, inner);
  p2_kernel<<<dim3(64*nks),  dim3(512), 0, stream>>>(inner, Bm, part, nks);
  if (nks > 1)
    reduce_kernel<<<dim3(512), dim3(256), 0, stream>>>(part, (float*)d_out, nks);
}

// Round 6
// 299.366 us; speedup vs baseline: 1.9318x; 1.0004x over previous
//
#include <hip/hip_runtime.h>
#include <hip/hip_bf16.h>
#include <stdint.h>

#define B_SZ   512
#define NINST  4
#define D_IN   1024
#define D_OUTD 1024
#define CCOMP  64
#define MRANK  256
#define KTOT   (CCOMP*MRANK)   // 16384

typedef __attribute__((ext_vector_type(4))) float  f32x4;
typedef __attribute__((ext_vector_type(8))) __bf16 bf16x8;
typedef __attribute__((ext_vector_type(4))) __bf16 bf16x4;

__device__ inline void gload_lds16(const __bf16* g, __bf16* l) {
  __builtin_amdgcn_global_load_lds(
      (const __attribute__((address_space(1))) void*)g,
      (__attribute__((address_space(3))) void*)l, 16, 0, 0);
}

// ---------------------------------------------------------------------------
// Prepass: xbf[i][b][k] = bf16(x[b][i][k]).  12 MB traffic, ~3 us.
// ---------------------------------------------------------------------------
__global__ __launch_bounds__(256)
void xcvt_kernel(const float* __restrict__ x, __bf16* __restrict__ xbf)
{
  const int total = (B_SZ*NINST*D_IN) / 4;
  for (int v = blockIdx.x*256 + threadIdx.x; v < total; v += gridDim.x*256) {
    const int k4 = v & 255;
    const int i  = (v >> 8) & 3;
    const int b  = v >> 10;
    f32x4 f = ((const f32x4*)x)[v];
    bf16x4 h; h[0]=(__bf16)f.x; h[1]=(__bf16)f.y; h[2]=(__bf16)f.z; h[3]=(__bf16)f.w;
    ((bf16x4*)xbf)[((size_t)i*B_SZ + b)*256 + k4] = h;
  }
}

// ---------------------------------------------------------------------------
// Phase 1: inner[i][b][c*256+m] = mask * (xbf . A).  grid 1024.
// Main loop unchanged from R5. NEW: LDS-transpose epilogue -> coalesced
// bf16x8 stores (replaces 64 scalar 2B global stores/thread).
// ---------------------------------------------------------------------------
__global__ __launch_bounds__(512, 2)
void p1_kernel(const __bf16* __restrict__ xbf, const float* __restrict__ A,
               const int* __restrict__ mask, __bf16* __restrict__ inner)
{
  const int bid = blockIdx.x;
  const int L   = (bid & 7) * 128 + (bid >> 3);
  const int ic  = L >> 2;
  const int i   = ic >> 6;
  const int c   = ic & 63;
  const int b0  = (L & 3) * 128;

  const int tid  = threadIdx.x;
  const int lane = tid & 63;
  const int wid  = tid >> 6;
  const int wr   = wid >> 2;
  const int wc   = wid & 3;

  // Xs [2][128][64] @0 (32 KB); As [2][256][64] @32768 (64 KB);
  // Ts [128][264] bf16 overlays As region (67584 B) -> total 100352 B.
  __shared__ __align__(16) char smem[100352];
  __bf16* Xs = (__bf16*)smem;
  __bf16* As = (__bf16*)(smem + 32768);
  __bf16* Ts = (__bf16*)(smem + 32768);
  __shared__ int Msk[128];

  if (tid < 128)
    Msk[tid] = mask[(size_t)(b0 + tid) * (NINST*CCOMP) + i*CCOMP + c];

  f32x4 acc[4][4];
#pragma unroll
  for (int a_ = 0; a_ < 4; ++a_)
#pragma unroll
    for (int b_ = 0; b_ < 4; ++b_)
      acc[a_][b_] = (f32x4){0.f, 0.f, 0.f, 0.f};

  const __bf16* xbase = xbf + ((size_t)i * B_SZ + b0) * D_IN;
  const float*  Abase = A + (size_t)ic * D_IN * MRANK;

  const int am = tid & 255;
  const int ag = tid >> 8;

  float areg[4][8];

  auto stageXs = [&](int buf, int kt) {
#pragma unroll
    for (int q = 0; q < 2; ++q) {
      const int ci  = wid*2 + q;
      const int row = ci*8 + (lane >> 3);
      const int kch = (lane & 7) ^ (row & 7);
      gload_lds16(xbase + (size_t)row * D_IN + kt*64 + kch*8,
                  Xs + buf*8192 + ci*512);
    }
  };
  auto loadA = [&](int kt) {
#pragma unroll
    for (int q = 0; q < 4; ++q)
#pragma unroll
      for (int j = 0; j < 8; ++j)
        areg[q][j] = Abase[(size_t)(kt*64 + (ag*4+q)*8 + j)*MRANK + am];
  };
  auto writeA = [&](int buf) {
#pragma unroll
    for (int q = 0; q < 4; ++q) {
      bf16x8 h;
#pragma unroll
      for (int j = 0; j < 8; ++j) h[j] = (__bf16)areg[q][j];
      *(bf16x8*)(As + buf*16384 + am*64 + (((ag*4+q) ^ (am & 7)))*8) = h;
    }
  };

  stageXs(0, 0); loadA(0); writeA(0);
  __syncthreads();

  int cur = 0;
  for (int kt = 0; kt < D_IN/64; ++kt) {
    if (kt+1 < D_IN/64) { stageXs(cur ^ 1, kt+1); loadA(kt+1); }
#pragma unroll
    for (int kk = 0; kk < 2; ++kk) {
      const int oct = kk*4 + (lane >> 4);
      bf16x8 af[4];
#pragma unroll
      for (int mi = 0; mi < 4; ++mi) {
        const int row = wr*64 + mi*16 + (lane & 15);
        af[mi] = *(const bf16x8*)(Xs + cur*8192 + row*64 + ((oct ^ (row & 7)))*8);
      }
#pragma unroll
      for (int ni = 0; ni < 4; ++ni) {
        const int col = wc*64 + ni*16 + (lane & 15);
        bf16x8 bfr = *(const bf16x8*)(As + cur*16384 + col*64 + ((oct ^ (col & 7)))*8);
#pragma unroll
        for (int mi = 0; mi < 4; ++mi)
          acc[mi][ni] = __builtin_amdgcn_mfma_f32_16x16x32_bf16(af[mi], bfr, acc[mi][ni], 0, 0, 0);
      }
    }
    if (kt+1 < D_IN/64) writeA(cur ^ 1);
    __syncthreads();
    cur ^= 1;
  }

  // ---- epilogue: acc -> Ts (masked bf16) -> coalesced global stores ----
#pragma unroll
  for (int mi = 0; mi < 4; ++mi)
#pragma unroll
    for (int ni = 0; ni < 4; ++ni) {
      const int colL = wc*64 + ni*16 + (lane & 15);
#pragma unroll
      for (int j = 0; j < 4; ++j) {
        const int rowL = wr*64 + mi*16 + (lane >> 4)*4 + j;
        Ts[rowL*264 + colL] = (__bf16)(acc[mi][ni][j] * (float)Msk[rowL]);
      }
    }
  __syncthreads();
  {
    __bf16* obase = inner + ((size_t)i * B_SZ + b0) * KTOT + (size_t)c * MRANK;
    const int tch = tid & 31, trow = tid >> 5;   // 32 lanes x 16B = 512B/row
#pragma unroll
    for (int p = 0; p < 8; ++p) {
      const int row = p*16 + trow;
      bf16x8 v = *(const bf16x8*)(&Ts[row*264 + tch*8]);
      *(bf16x8*)(obase + (size_t)row * KTOT + tch*8) = v;
    }
  }
}

// ---------------------------------------------------------------------------
// Phase 2: part[ks][b][i][o] = sum_{K slice} inner . Bflat.  grid 64*nks.
// Main loop unchanged. NEW: LDS-transpose epilogue (f32, pad 268),
// one contiguous 1KB wave-row store per row.
// ---------------------------------------------------------------------------
__global__ __launch_bounds__(512, 2)
void p2_kernel(const __bf16* __restrict__ inner, const float* __restrict__ Bm,
               float* __restrict__ dst, int nks)
{
  const int bid = blockIdx.x;
  const int L   = (bid & 7) * (gridDim.x >> 3) + (bid >> 3);
  const int bt  = L & 3;
  const int nt  = (L >> 2) & 3;
  const int rest = L >> 4;
  const int ks  = rest % nks;
  const int i   = rest / nks;
  const int b0  = bt * 128;
  const int o0  = nt * 256;
  const int NSTEP = (KTOT/64) / nks;
  const int kb0   = ks * NSTEP;

  const int tid  = threadIdx.x;
  const int lane = tid & 63;
  const int wid  = tid >> 6;
  const int wr   = wid >> 2;
  const int wc   = wid & 3;

  // Is [2][128][64] @0 (32 KB); Bs [2][256][64] @32768 (64 KB);
  // Ls [128][268] f32 overlays everything (137216 B total).
  __shared__ __align__(16) char smem[137216];
  __bf16* Is = (__bf16*)smem;
  __bf16* Bs = (__bf16*)(smem + 32768);
  float*  Ls = (float*)smem;

  f32x4 acc[4][4];
#pragma unroll
  for (int a_ = 0; a_ < 4; ++a_)
#pragma unroll
    for (int b_ = 0; b_ < 4; ++b_)
      acc[a_][b_] = (f32x4){0.f, 0.f, 0.f, 0.f};

  const __bf16* ibase = inner + ((size_t)i * B_SZ + b0) * KTOT;
  const float*  Bbase = Bm + (size_t)i * KTOT * D_OUTD + o0;

  const int bo = tid & 255;
  const int bg = tid >> 8;

  float breg[4][8];

  auto stageIs = [&](int buf, int kt) {
#pragma unroll
    for (int q = 0; q < 2; ++q) {
      const int ci  = wid*2 + q;
      const int row = ci*8 + (lane >> 3);
      const int kch = (lane & 7) ^ (row & 7);
      gload_lds16(ibase + (size_t)row * KTOT + kt*64 + kch*8,
                  Is + buf*8192 + ci*512);
    }
  };
  auto loadB = [&](int kt) {
#pragma unroll
    for (int q = 0; q < 4; ++q)
#pragma unroll
      for (int j = 0; j < 8; ++j)
        breg[q][j] = Bbase[(size_t)(kt*64 + (bg*4+q)*8 + j)*D_OUTD + bo];
  };
  auto writeB = [&](int buf) {
#pragma unroll
    for (int q = 0; q < 4; ++q) {
      bf16x8 h;
#pragma unroll
      for (int j = 0; j < 8; ++j) h[j] = (__bf16)breg[q][j];
      *(bf16x8*)(Bs + buf*16384 + bo*64 + (((bg*4+q) ^ (bo & 7)))*8) = h;
    }
  };

  stageIs(0, kb0); loadB(kb0); writeB(0);
  __syncthreads();

  int cur = 0;
  for (int t = 0; t < NSTEP; ++t) {
    if (t+1 < NSTEP) { stageIs(cur ^ 1, kb0 + t + 1); loadB(kb0 + t + 1); }
#pragma unroll
    for (int kk = 0; kk < 2; ++kk) {
      const int oct = kk*4 + (lane >> 4);
      bf16x8 af[4];
#pragma unroll
      for (int mi = 0; mi < 4; ++mi) {
        const int row = wr*64 + mi*16 + (lane & 15);
        af[mi] = *(const bf16x8*)(Is + cur*8192 + row*64 + ((oct ^ (row & 7)))*8);
      }
#pragma unroll
      for (int ni = 0; ni < 4; ++ni) {
        const int col = wc*64 + ni*16 + (lane & 15);
        bf16x8 bfr = *(const bf16x8*)(Bs + cur*16384 + col*64 + ((oct ^ (col & 7)))*8);
#pragma unroll
        for (int mi = 0; mi < 4; ++mi)
          acc[mi][ni] = __builtin_amdgcn_mfma_f32_16x16x32_bf16(af[mi], bfr, acc[mi][ni], 0, 0, 0);
      }
    }
    if (t+1 < NSTEP) writeB(cur ^ 1);
    __syncthreads();
    cur ^= 1;
  }

  // ---- epilogue: acc -> Ls (f32) -> coalesced 1KB wave-row stores ----
#pragma unroll
  for (int mi = 0; mi < 4; ++mi)
#pragma unroll
    for (int ni = 0; ni < 4; ++ni) {
      const int colL = wc*64 + ni*16 + (lane & 15);
      const int rbase = wr*64 + mi*16 + (lane >> 4)*4;
#pragma unroll
      for (int j = 0; j < 4; ++j)
        Ls[(rbase + j)*268 + colL] = acc[mi][ni][j];
    }
  __syncthreads();
  {
    float* obase = dst + (size_t)ks * ((size_t)B_SZ*NINST*D_OUTD)
                 + ((size_t)b0 * NINST + i) * D_OUTD + o0;
#pragma unroll
    for (int p = 0; p < 16; ++p) {
      const int row = p*8 + wid;                 // one wave per row
      f32x4 v = *(const f32x4*)(&Ls[row*268 + lane*4]);
      *(f32x4*)(obase + (size_t)row * (NINST*D_OUTD) + lane*4) = v;
    }
  }
}

__global__ __launch_bounds__(256)
void reduce_kernel(const float* __restrict__ part, float* __restrict__ out, int nks)
{
  const int total = (B_SZ*NINST*D_OUTD) / 4;
  for (int v = blockIdx.x*256 + threadIdx.x; v < total; v += gridDim.x*256) {
    f32x4 s = ((const f32x4*)part)[v];
    for (int ks = 1; ks < nks; ++ks)
      s += ((const f32x4*)part)[(size_t)ks*total + v];
    ((f32x4*)out)[v] = s;
  }
}

extern "C" void kernel_launch(void* const* d_in, const int* in_sizes, int n_in,
                              void* d_out, int out_size, void* d_ws, size_t ws_size,
                              hipStream_t stream) {
  const float* x    = (const float*)d_in[0];
  const float* A    = (const float*)d_in[1];
  const float* Bm   = (const float*)d_in[2];
  const int*   mask = (const int*)d_in[3];

  const size_t innerB = (size_t)NINST * B_SZ * KTOT * 2;       // 64 MB
  const size_t xbfB   = (size_t)NINST * B_SZ * D_IN * 2;       // 4 MB
  const size_t partB  = (size_t)B_SZ * NINST * D_OUTD * 4;     // 8 MB per split

  __bf16* inner = (__bf16*)d_ws;
  __bf16* xbf   = (__bf16*)((char*)d_ws + innerB);

  int nks = 1;
  if      (ws_size >= innerB + xbfB + 4*partB) nks = 4;
  else if (ws_size >= innerB + xbfB + 2*partB) nks = 2;
  float* part = (nks > 1) ? (float*)((char*)d_ws + innerB + xbfB) : (float*)d_out;

  xcvt_kernel<<<dim3(1024),  dim3(256), 0, stream>>>(x, xbf);
  p1_kernel<<<dim3(1024),    dim3(512), 0, stream>>>(xbf, A, mask, inner);
  p2_kernel<<<dim3(64*nks),  dim3(512), 0, stream>>>(inner, Bm, part, nks);
  if (nks > 1)
    reduce_kernel<<<dim3(512), dim3(256), 0, stream>>>(part, (float*)d_out, nks);
}

// Round 7
// 280.659 us; speedup vs baseline: 2.0605x; 1.0667x over previous
//
#include <hip/hip_runtime.h>
#include <hip/hip_bf16.h>
#include <stdint.h>

#define B_SZ   512
#define NINST  4
#define D_IN   1024
#define D_OUTD 1024
#define CCOMP  64
#define MRANK  256
#define KTOT   (CCOMP*MRANK)   // 16384

typedef __attribute__((ext_vector_type(4))) float  f32x4;
typedef __attribute__((ext_vector_type(8))) __bf16 bf16x8;
typedef __attribute__((ext_vector_type(4))) __bf16 bf16x4;

__device__ inline void gload_lds16(const __bf16* g, __bf16* l) {
  __builtin_amdgcn_global_load_lds(
      (const __attribute__((address_space(1))) void*)g,
      (__attribute__((address_space(3))) void*)l, 16, 0, 0);
}

// ---------------------------------------------------------------------------
// Prepass: xbf[i][b][k] = bf16(x[b][i][k]).  12 MB traffic, ~3 us.
// ---------------------------------------------------------------------------
__global__ __launch_bounds__(256)
void xcvt_kernel(const float* __restrict__ x, __bf16* __restrict__ xbf)
{
  const int total = (B_SZ*NINST*D_IN) / 4;
  for (int v = blockIdx.x*256 + threadIdx.x; v < total; v += gridDim.x*256) {
    const int k4 = v & 255;
    const int i  = (v >> 8) & 3;
    const int b  = v >> 10;
    f32x4 f = ((const f32x4*)x)[v];
    bf16x4 h; h[0]=(__bf16)f.x; h[1]=(__bf16)f.y; h[2]=(__bf16)f.z; h[3]=(__bf16)f.w;
    ((bf16x4*)xbf)[((size_t)i*B_SZ + b)*256 + k4] = h;
  }
}

// ---------------------------------------------------------------------------
// Phase 1: inner[i][b][c*256+m] = mask * (xbf . A).
// 256 thr / 4 waves, tile 128(b) x 64(m), BK=64, dbuf, LDS 48.5 KB
// -> 3 blocks/CU (12 waves): cross-block latency hiding.
// grid 4096 = 256 ic x 4 mt x 4 bt, XCD-chunked (A bt-sharers adjacent).
// ---------------------------------------------------------------------------
__global__ __launch_bounds__(256, 3)
void p1_kernel(const __bf16* __restrict__ xbf, const float* __restrict__ A,
               const int* __restrict__ mask, __bf16* __restrict__ inner)
{
  const int bid = blockIdx.x;
  const int L   = (bid & 7) * 512 + (bid >> 3);
  const int bt  = L & 3;
  const int mt  = (L >> 2) & 3;
  const int ic  = L >> 4;          // 0..255
  const int i   = ic >> 6;
  const int c   = ic & 63;
  const int b0  = bt * 128;
  const int m0  = mt * 64;

  const int tid  = threadIdx.x;
  const int lane = tid & 63;
  const int wid  = tid >> 6;       // 0..3
  const int wr   = wid >> 1;       // 0..1 : 64-row strip
  const int wc   = wid & 1;        // 0..1 : 32-col strip

  // Xs [2][128][64] @0 (32 KB); As [2][64][64] @32768 (16 KB);
  // Ts [128][72] bf16 overlays Xs after final barrier; Msk separate.
  __shared__ __align__(16) char smem[49664];
  __bf16* Xs = (__bf16*)smem;
  __bf16* As = (__bf16*)(smem + 32768);
  __bf16* Ts = (__bf16*)smem;
  int*    Msk = (int*)(smem + 49152);

  if (tid < 128)
    Msk[tid] = mask[(size_t)(b0 + tid) * (NINST*CCOMP) + i*CCOMP + c];

  f32x4 acc[4][2];
#pragma unroll
  for (int a_ = 0; a_ < 4; ++a_)
#pragma unroll
    for (int b_ = 0; b_ < 2; ++b_)
      acc[a_][b_] = (f32x4){0.f, 0.f, 0.f, 0.f};

  const __bf16* xbase = xbf + ((size_t)i * B_SZ + b0) * D_IN;
  const float*  Abase = A + (size_t)ic * D_IN * MRANK + m0;

  const int am = tid & 63;         // A column (m within 64)
  const int ag = tid >> 6;         // 0..3 -> 2 k-octets each

  float areg[2][8];

  auto stageXs = [&](int buf, int kt) {
#pragma unroll
    for (int q = 0; q < 4; ++q) {
      const int ci  = wid*4 + q;                 // 0..15, wave-uniform
      const int row = ci*8 + (lane >> 3);
      const int kch = (lane & 7) ^ (row & 7);    // pre-swizzled source
      gload_lds16(xbase + (size_t)row * D_IN + kt*64 + kch*8,
                  Xs + buf*8192 + ci*512);
    }
  };
  auto loadA = [&](int kt) {
#pragma unroll
    for (int q = 0; q < 2; ++q)
#pragma unroll
      for (int j = 0; j < 8; ++j)
        areg[q][j] = Abase[(size_t)(kt*64 + (ag*2+q)*8 + j)*MRANK + am];
  };
  auto writeA = [&](int buf) {
#pragma unroll
    for (int q = 0; q < 2; ++q) {
      const int oct = ag*2 + q;
      bf16x8 h;
#pragma unroll
      for (int j = 0; j < 8; ++j) h[j] = (__bf16)areg[q][j];
      *(bf16x8*)(As + buf*4096 + am*64 + ((oct ^ (am & 7)))*8) = h;
    }
  };

  stageXs(0, 0); loadA(0); writeA(0);
  __syncthreads();

  int cur = 0;
  for (int kt = 0; kt < D_IN/64; ++kt) {
    if (kt+1 < D_IN/64) { stageXs(cur ^ 1, kt+1); loadA(kt+1); }
#pragma unroll
    for (int kk = 0; kk < 2; ++kk) {
      const int oct = kk*4 + (lane >> 4);
      bf16x8 af[4];
#pragma unroll
      for (int mi = 0; mi < 4; ++mi) {
        const int row = wr*64 + mi*16 + (lane & 15);
        af[mi] = *(const bf16x8*)(Xs + cur*8192 + row*64 + ((oct ^ (row & 7)))*8);
      }
#pragma unroll
      for (int ni = 0; ni < 2; ++ni) {
        const int col = wc*32 + ni*16 + (lane & 15);
        bf16x8 bfr = *(const bf16x8*)(As + cur*4096 + col*64 + ((oct ^ (col & 7)))*8);
#pragma unroll
        for (int mi = 0; mi < 4; ++mi)
          acc[mi][ni] = __builtin_amdgcn_mfma_f32_16x16x32_bf16(af[mi], bfr, acc[mi][ni], 0, 0, 0);
      }
    }
    if (kt+1 < D_IN/64) writeA(cur ^ 1);
    __syncthreads();
    cur ^= 1;
  }

  // ---- epilogue: acc -> Ts overlay (masked bf16) -> coalesced stores ----
#pragma unroll
  for (int mi = 0; mi < 4; ++mi)
#pragma unroll
    for (int ni = 0; ni < 2; ++ni) {
      const int colL = wc*32 + ni*16 + (lane & 15);
#pragma unroll
      for (int j = 0; j < 4; ++j) {
        const int rowL = wr*64 + mi*16 + (lane >> 4)*4 + j;
        Ts[rowL*72 + colL] = (__bf16)(acc[mi][ni][j] * (float)Msk[rowL]);
      }
    }
  __syncthreads();
  {
    __bf16* obase = inner + ((size_t)i * B_SZ + b0) * KTOT + (size_t)c * MRANK + m0;
    const int tch = tid & 7, trow = tid >> 3;    // 8 chunks x 32 rows/pass
#pragma unroll
    for (int p = 0; p < 4; ++p) {
      const int row = p*32 + trow;
      bf16x8 v = *(const bf16x8*)(&Ts[row*72 + tch*8]);
      *(bf16x8*)(obase + (size_t)row * KTOT + tch*8) = v;
    }
  }
}

// ---------------------------------------------------------------------------
// Phase 2: part[ks][b][i][o] = sum_{K slice} inner . Bflat.
// 256 thr / 4 waves, tile 128(b) x 128(o), BK=64, dbuf, LDS 64 KB
// -> 2 independent blocks/CU. grid 512 = (i,ks)16 x nt8 x bt4, XCD-chunked.
// ---------------------------------------------------------------------------
__global__ __launch_bounds__(256, 2)
void p2_kernel(const __bf16* __restrict__ inner, const float* __restrict__ Bm,
               float* __restrict__ dst, int nks)
{
  const int bid = blockIdx.x;
  const int L   = (bid & 7) * (gridDim.x >> 3) + (bid >> 3);
  const int bt  = L & 3;
  const int nt  = (L >> 2) & 7;
  const int rest = L >> 5;         // i*nks + ks
  const int ks  = rest % nks;
  const int i   = rest / nks;
  const int b0  = bt * 128;
  const int o0  = nt * 128;
  const int NSTEP = (KTOT/64) / nks;
  const int kb0   = ks * NSTEP;

  const int tid  = threadIdx.x;
  const int lane = tid & 63;
  const int wid  = tid >> 6;       // 0..3
  const int wr   = wid >> 1;       // 0..1 : 64-row strip
  const int wc   = wid & 1;        // 0..1 : 64-col strip

  __shared__ __align__(16) char smem[65536];
  __bf16* Is = (__bf16*)smem;             // [2][128][64]
  __bf16* Bs = (__bf16*)(smem + 32768);   // [2][128][64] n-major

  f32x4 acc[4][4];
#pragma unroll
  for (int a_ = 0; a_ < 4; ++a_)
#pragma unroll
    for (int b_ = 0; b_ < 4; ++b_)
      acc[a_][b_] = (f32x4){0.f, 0.f, 0.f, 0.f};

  const __bf16* ibase = inner + ((size_t)i * B_SZ + b0) * KTOT;
  const float*  Bbase = Bm + (size_t)i * KTOT * D_OUTD + o0;

  const int bo = tid & 127;        // B column o
  const int bg = tid >> 7;         // 0..1 -> 4 k-octets each

  float breg[4][8];

  auto stageIs = [&](int buf, int kt) {
#pragma unroll
    for (int q = 0; q < 4; ++q) {
      const int ci  = wid*4 + q;                 // 0..15, wave-uniform
      const int row = ci*8 + (lane >> 3);
      const int kch = (lane & 7) ^ (row & 7);    // pre-swizzled source
      gload_lds16(ibase + (size_t)row * KTOT + kt*64 + kch*8,
                  Is + buf*8192 + ci*512);
    }
  };
  auto loadB = [&](int kt) {
#pragma unroll
    for (int q = 0; q < 4; ++q)
#pragma unroll
      for (int j = 0; j < 8; ++j)
        breg[q][j] = Bbase[(size_t)(kt*64 + (bg*4+q)*8 + j)*D_OUTD + bo];
  };
  auto writeB = [&](int buf) {
#pragma unroll
    for (int q = 0; q < 4; ++q) {
      const int oct = bg*4 + q;
      bf16x8 h;
#pragma unroll
      for (int j = 0; j < 8; ++j) h[j] = (__bf16)breg[q][j];
      *(bf16x8*)(Bs + buf*8192 + bo*64 + ((oct ^ (bo & 7)))*8) = h;
    }
  };

  stageIs(0, kb0); loadB(kb0); writeB(0);
  __syncthreads();

  int cur = 0;
  for (int t = 0; t < NSTEP; ++t) {
    if (t+1 < NSTEP) { stageIs(cur ^ 1, kb0 + t + 1); loadB(kb0 + t + 1); }
#pragma unroll
    for (int kk = 0; kk < 2; ++kk) {
      const int oct = kk*4 + (lane >> 4);
      bf16x8 af[4];
#pragma unroll
      for (int mi = 0; mi < 4; ++mi) {
        const int row = wr*64 + mi*16 + (lane & 15);
        af[mi] = *(const bf16x8*)(Is + cur*8192 + row*64 + ((oct ^ (row & 7)))*8);
      }
#pragma unroll
      for (int ni = 0; ni < 4; ++ni) {
        const int col = wc*64 + ni*16 + (lane & 15);
        bf16x8 bfr = *(const bf16x8*)(Bs + cur*8192 + col*64 + ((oct ^ (col & 7)))*8);
#pragma unroll
        for (int mi = 0; mi < 4; ++mi)
          acc[mi][ni] = __builtin_amdgcn_mfma_f32_16x16x32_bf16(af[mi], bfr, acc[mi][ni], 0, 0, 0);
      }
    }
    if (t+1 < NSTEP) writeB(cur ^ 1);
    __syncthreads();
    cur ^= 1;
  }

  // ---- epilogue: direct f32 stores (R4-proven) ----
  float* obase = dst + (size_t)ks * ((size_t)B_SZ*NINST*D_OUTD)
               + ((size_t)b0 * NINST + i) * D_OUTD + o0;
#pragma unroll
  for (int mi = 0; mi < 4; ++mi)
#pragma unroll
    for (int ni = 0; ni < 4; ++ni) {
      const int colL = wc*64 + ni*16 + (lane & 15);
#pragma unroll
      for (int j = 0; j < 4; ++j) {
        const int rowL = wr*64 + mi*16 + (lane >> 4)*4 + j;
        obase[(size_t)rowL * (NINST*D_OUTD) + colL] = acc[mi][ni][j];
      }
    }
}

__global__ __launch_bounds__(256)
void reduce_kernel(const float* __restrict__ part, float* __restrict__ out, int nks)
{
  const int total = (B_SZ*NINST*D_OUTD) / 4;
  for (int v = blockIdx.x*256 + threadIdx.x; v < total; v += gridDim.x*256) {
    f32x4 s = ((const f32x4*)part)[v];
    for (int ks = 1; ks < nks; ++ks)
      s += ((const f32x4*)part)[(size_t)ks*total + v];
    ((f32x4*)out)[v] = s;
  }
}

extern "C" void kernel_launch(void* const* d_in, const int* in_sizes, int n_in,
                              void* d_out, int out_size, void* d_ws, size_t ws_size,
                              hipStream_t stream) {
  const float* x    = (const float*)d_in[0];
  const float* A    = (const float*)d_in[1];
  const float* Bm   = (const float*)d_in[2];
  const int*   mask = (const int*)d_in[3];

  const size_t innerB = (size_t)NINST * B_SZ * KTOT * 2;       // 64 MB
  const size_t xbfB   = (size_t)NINST * B_SZ * D_IN * 2;       // 4 MB
  const size_t partB  = (size_t)B_SZ * NINST * D_OUTD * 4;     // 8 MB per split

  __bf16* inner = (__bf16*)d_ws;
  __bf16* xbf   = (__bf16*)((char*)d_ws + innerB);

  int nks = 1;
  if      (ws_size >= innerB + xbfB + 4*partB) nks = 4;
  else if (ws_size >= innerB + xbfB + 2*partB) nks = 2;
  float* part = (nks > 1) ? (float*)((char*)d_ws + innerB + xbfB) : (float*)d_out;

  xcvt_kernel<<<dim3(1024),   dim3(256), 0, stream>>>(x, xbf);
  p1_kernel<<<dim3(4096),     dim3(256), 0, stream>>>(xbf, A, mask, inner);
  p2_kernel<<<dim3(128*nks),  dim3(256), 0, stream>>>(inner, Bm, part, nks);
  if (nks > 1)
    reduce_kernel<<<dim3(512), dim3(256), 0, stream>>>(part, (float*)d_out, nks);
}

// Round 8
// 274.057 us; speedup vs baseline: 2.1102x; 1.0241x over previous
//
#include <hip/hip_runtime.h>
#include <hip/hip_bf16.h>
#include <stdint.h>

#define B_SZ   512
#define NINST  4
#define D_IN   1024
#define D_OUTD 1024
#define CCOMP  64
#define MRANK  256
#define KTOT   (CCOMP*MRANK)   // 16384

typedef __attribute__((ext_vector_type(4))) float  f32x4;
typedef __attribute__((ext_vector_type(8))) __bf16 bf16x8;
typedef __attribute__((ext_vector_type(4))) __bf16 bf16x4;

__device__ inline void gload_lds16(const __bf16* g, __bf16* l) {
  __builtin_amdgcn_global_load_lds(
      (const __attribute__((address_space(1))) void*)g,
      (__attribute__((address_space(3))) void*)l, 16, 0, 0);
}

// ---------------------------------------------------------------------------
// Prepass A: xbf[i][b][k] = bf16(x[b][i][k]).  12 MB traffic, ~3 us.
// ---------------------------------------------------------------------------
__global__ __launch_bounds__(256)
void xcvt_kernel(const float* __restrict__ x, __bf16* __restrict__ xbf)
{
  const int total = (B_SZ*NINST*D_IN) / 4;
  for (int v = blockIdx.x*256 + threadIdx.x; v < total; v += gridDim.x*256) {
    const int k4 = v & 255;
    const int i  = (v >> 8) & 3;
    const int b  = v >> 10;
    f32x4 f = ((const f32x4*)x)[v];
    bf16x4 h; h[0]=(__bf16)f.x; h[1]=(__bf16)f.y; h[2]=(__bf16)f.z; h[3]=(__bf16)f.w;
    ((bf16x4*)xbf)[((size_t)i*B_SZ + b)*256 + k4] = h;
  }
}

// ---------------------------------------------------------------------------
// Prepass B: per (i,c), permutation gidx[ic][0..511] with the cnt active
// b-rows (mask!=0) first, inactive after; cnts[ic] = active count.
// ---------------------------------------------------------------------------
__global__ __launch_bounds__(512)
void maskscan_kernel(const int* __restrict__ mask, int* __restrict__ gidx,
                     int* __restrict__ cnts)
{
  const int ic = blockIdx.x;           // i*64 + c
  const int i  = ic >> 6;
  const int c  = ic & 63;
  const int b  = threadIdx.x;          // 0..511
  const int lane = b & 63, w = b >> 6;

  __shared__ int wact[8], wbaseA[8], wbaseI[8];

  const int m = mask[((size_t)b * NINST + i) * CCOMP + c] != 0;
  unsigned long long bal = __ballot(m);
  const int ap = __popcll(bal & ((lane == 63) ? ~0ull >> 1 : ((1ull << lane) - 1)) & ((1ull << lane) - 1));
  if (lane == 0) wact[w] = __popcll(bal);
  __syncthreads();
  if (b == 0) {
    int tot = 0;
    for (int k = 0; k < 8; ++k) tot += wact[k];
    int accA = 0, accI = 0;
    for (int k = 0; k < 8; ++k) {
      wbaseA[k] = accA;        accA += wact[k];
      wbaseI[k] = tot + accI;  accI += 64 - wact[k];
    }
    cnts[ic] = tot;
  }
  __syncthreads();
  const int pos = m ? (wbaseA[w] + ap) : (wbaseI[w] + (lane - ap));
  gidx[(size_t)ic * 512 + pos] = b;
}

// ---------------------------------------------------------------------------
// Phase 1 (p2-shape + row compaction): for each (i,c), only the cnt active
// b-rows are computed; inactive rows get zero-stores.  Tile 128(brows) x
// 128(m), BK=64, 256 thr / 4 waves, dbuf, ~66 KB LDS -> 2 blocks/CU.
// grid 2048 = 256 ic x 2 mt x 4 bt (bt = compacted-row tile), XCD-chunked.
// X gathered per-lane via global_load_lds source (m173); A staged like p2's B.
// ---------------------------------------------------------------------------
__global__ __launch_bounds__(256, 2)
void p1_kernel(const __bf16* __restrict__ xbf, const float* __restrict__ A,
               const int* __restrict__ gidx, const int* __restrict__ cnts,
               __bf16* __restrict__ inner)
{
  const int bid = blockIdx.x;
  const int L   = (bid & 7) * 256 + (bid >> 3);
  const int bt  = L & 3;
  const int mt  = (L >> 2) & 1;
  const int ic  = L >> 3;          // 0..255
  const int i   = ic >> 6;
  const int c   = ic & 63;
  const int b0  = bt * 128;        // compacted-row base
  const int m0  = mt * 128;

  const int tid  = threadIdx.x;
  const int lane = tid & 63;
  const int wid  = tid >> 6;       // 0..3
  const int wr   = wid >> 1;       // 0..1 : 64-row strip
  const int wc   = wid & 1;        // 0..1 : 64-col strip

  // Xs [2][128][64] @0 (32 KB); As [2][128][64] @32768 (32 KB);
  // Ts [128][132] bf16 (33.5 KB) overlays smem after final barrier.
  __shared__ __align__(16) char smem[65536];
  __bf16* Xs = (__bf16*)smem;
  __bf16* As = (__bf16*)(smem + 32768);
  __bf16* Ts = (__bf16*)smem;
  __shared__ int Gix[128];
  __shared__ int sCnt;

  if (tid < 128) Gix[tid] = gidx[(size_t)ic * 512 + b0 + tid];
  if (tid == 0)  sCnt = cnts[ic];
  __syncthreads();
  const int cnt = sCnt;

  __bf16* obase = inner + (size_t)i * B_SZ * KTOT + (size_t)c * MRANK + m0;

  if (b0 >= cnt) {
    // all 128 rows inactive: scatter zero rows, done.
    bf16x8 z = {};
    const int tch = tid & 15, trow = tid >> 4;   // 16 chunks x 16 rows/pass
#pragma unroll
    for (int p = 0; p < 8; ++p) {
      const int row = p*16 + trow;
      *(bf16x8*)(obase + (size_t)Gix[row] * KTOT + tch*8) = z;
    }
    return;
  }

  f32x4 acc[4][4];
#pragma unroll
  for (int a_ = 0; a_ < 4; ++a_)
#pragma unroll
    for (int b_ = 0; b_ < 4; ++b_)
      acc[a_][b_] = (f32x4){0.f, 0.f, 0.f, 0.f};

  const float* Abase = A + (size_t)ic * D_IN * MRANK + m0;

  // ---- X gather-staging setup: each thread owns 4 fixed rows ----
  const int rq  = lane >> 3;           // row-within-8
  const int kch = (lane & 7);          // chunk id (pre-swizzled below)
  const __bf16* srcX[4];
#pragma unroll
  for (int q = 0; q < 4; ++q) {
    const int ci  = wid*4 + q;         // 0..15, wave-uniform dest block
    const int row = ci*8 + rq;         // tile row 0..127
    const int kc  = kch ^ (row & 7);   // pre-swizzle the SOURCE chunk
    srcX[q] = xbf + ((size_t)i * B_SZ + Gix[row]) * D_IN + kc*8;
  }

  auto stageXs = [&](int buf, int kt) {
#pragma unroll
    for (int q = 0; q < 4; ++q) {
      const int ci = wid*4 + q;
      gload_lds16(srcX[q] + kt*64, Xs + buf*8192 + ci*512);
    }
  };

  const int bo = tid & 127;        // A column m (within 128)
  const int bg = tid >> 7;         // 0..1 -> 4 k-octets each
  float areg[4][8];

  auto loadA = [&](int kt) {
#pragma unroll
    for (int q = 0; q < 4; ++q)
#pragma unroll
      for (int j = 0; j < 8; ++j)
        areg[q][j] = Abase[(size_t)(kt*64 + (bg*4+q)*8 + j)*MRANK + bo];
  };
  auto writeA = [&](int buf) {
#pragma unroll
    for (int q = 0; q < 4; ++q) {
      const int oct = bg*4 + q;
      bf16x8 h;
#pragma unroll
      for (int j = 0; j < 8; ++j) h[j] = (__bf16)areg[q][j];
      *(bf16x8*)(As + buf*8192 + bo*64 + ((oct ^ (bo & 7)))*8) = h;
    }
  };

  stageXs(0, 0); loadA(0); writeA(0);
  __syncthreads();

  int cur = 0;
  for (int kt = 0; kt < D_IN/64; ++kt) {
    if (kt+1 < D_IN/64) { stageXs(cur ^ 1, kt+1); loadA(kt+1); }
#pragma unroll
    for (int kk = 0; kk < 2; ++kk) {
      const int oct = kk*4 + (lane >> 4);
      bf16x8 af[4];
#pragma unroll
      for (int mi = 0; mi < 4; ++mi) {
        const int row = wr*64 + mi*16 + (lane & 15);
        af[mi] = *(const bf16x8*)(Xs + cur*8192 + row*64 + ((oct ^ (row & 7)))*8);
      }
#pragma unroll
      for (int ni = 0; ni < 4; ++ni) {
        const int col = wc*64 + ni*16 + (lane & 15);
        bf16x8 bfr = *(const bf16x8*)(As + cur*8192 + col*64 + ((oct ^ (col & 7)))*8);
#pragma unroll
        for (int mi = 0; mi < 4; ++mi)
          acc[mi][ni] = __builtin_amdgcn_mfma_f32_16x16x32_bf16(af[mi], bfr, acc[mi][ni], 0, 0, 0);
      }
    }
    if (kt+1 < D_IN/64) writeA(cur ^ 1);
    __syncthreads();
    cur ^= 1;
  }

  // ---- epilogue: acc -> Ts (zero rows >= cnt) -> scattered row stores ----
  const int rlim = cnt - b0;           // rows < rlim are active
#pragma unroll
  for (int mi = 0; mi < 4; ++mi)
#pragma unroll
    for (int ni = 0; ni < 4; ++ni) {
      const int colL = wc*64 + ni*16 + (lane & 15);
#pragma unroll
      for (int j = 0; j < 4; ++j) {
        const int rowL = wr*64 + mi*16 + (lane >> 4)*4 + j;
        Ts[rowL*132 + colL] = (__bf16)((rowL < rlim) ? acc[mi][ni][j] : 0.f);
      }
    }
  __syncthreads();
  {
    const int tch = tid & 15, trow = tid >> 4;   // 16 chunks x 16 rows/pass
#pragma unroll
    for (int p = 0; p < 8; ++p) {
      const int row = p*16 + trow;
      bf16x8 v = *(const bf16x8*)(&Ts[row*132 + tch*8]);
      *(bf16x8*)(obase + (size_t)Gix[row] * KTOT + tch*8) = v;
    }
  }
}

// ---------------------------------------------------------------------------
// Phase 2: part[ks][b][i][o] = sum_{K slice} inner . Bflat.  (unchanged R7)
// 256 thr / 4 waves, tile 128(b) x 128(o), BK=64, dbuf, LDS 64 KB, 2/CU.
// ---------------------------------------------------------------------------
__global__ __launch_bounds__(256, 2)
void p2_kernel(const __bf16* __restrict__ inner, const float* __restrict__ Bm,
               float* __restrict__ dst, int nks)
{
  const int bid = blockIdx.x;
  const int L   = (bid & 7) * (gridDim.x >> 3) + (bid >> 3);
  const int bt  = L & 3;
  const int nt  = (L >> 2) & 7;
  const int rest = L >> 5;         // i*nks + ks
  const int ks  = rest % nks;
  const int i   = rest / nks;
  const int b0  = bt * 128;
  const int o0  = nt * 128;
  const int NSTEP = (KTOT/64) / nks;
  const int kb0   = ks * NSTEP;

  const int tid  = threadIdx.x;
  const int lane = tid & 63;
  const int wid  = tid >> 6;
  const int wr   = wid >> 1;
  const int wc   = wid & 1;

  __shared__ __align__(16) char smem[65536];
  __bf16* Is = (__bf16*)smem;             // [2][128][64]
  __bf16* Bs = (__bf16*)(smem + 32768);   // [2][128][64] n-major

  f32x4 acc[4][4];
#pragma unroll
  for (int a_ = 0; a_ < 4; ++a_)
#pragma unroll
    for (int b_ = 0; b_ < 4; ++b_)
      acc[a_][b_] = (f32x4){0.f, 0.f, 0.f, 0.f};

  const __bf16* ibase = inner + ((size_t)i * B_SZ + b0) * KTOT;
  const float*  Bbase = Bm + (size_t)i * KTOT * D_OUTD + o0;

  const int bo = tid & 127;
  const int bg = tid >> 7;

  float breg[4][8];

  auto stageIs = [&](int buf, int kt) {
#pragma unroll
    for (int q = 0; q < 4; ++q) {
      const int ci  = wid*4 + q;
      const int row = ci*8 + (lane >> 3);
      const int kch = (lane & 7) ^ (row & 7);
      gload_lds16(ibase + (size_t)row * KTOT + kt*64 + kch*8,
                  Is + buf*8192 + ci*512);
    }
  };
  auto loadB = [&](int kt) {
#pragma unroll
    for (int q = 0; q < 4; ++q)
#pragma unroll
      for (int j = 0; j < 8; ++j)
        breg[q][j] = Bbase[(size_t)(kt*64 + (bg*4+q)*8 + j)*D_OUTD + bo];
  };
  auto writeB = [&](int buf) {
#pragma unroll
    for (int q = 0; q < 4; ++q) {
      const int oct = bg*4 + q;
      bf16x8 h;
#pragma unroll
      for (int j = 0; j < 8; ++j) h[j] = (__bf16)breg[q][j];
      *(bf16x8*)(Bs + buf*8192 + bo*64 + ((oct ^ (bo & 7)))*8) = h;
    }
  };

  stageIs(0, kb0); loadB(kb0); writeB(0);
  __syncthreads();

  int cur = 0;
  for (int t = 0; t < NSTEP; ++t) {
    if (t+1 < NSTEP) { stageIs(cur ^ 1, kb0 + t + 1); loadB(kb0 + t + 1); }
#pragma unroll
    for (int kk = 0; kk < 2; ++kk) {
      const int oct = kk*4 + (lane >> 4);
      bf16x8 af[4];
#pragma unroll
      for (int mi = 0; mi < 4; ++mi) {
        const int row = wr*64 + mi*16 + (lane & 15);
        af[mi] = *(const bf16x8*)(Is + cur*8192 + row*64 + ((oct ^ (row & 7)))*8);
      }
#pragma unroll
      for (int ni = 0; ni < 4; ++ni) {
        const int col = wc*64 + ni*16 + (lane & 15);
        bf16x8 bfr = *(const bf16x8*)(Bs + cur*8192 + col*64 + ((oct ^ (col & 7)))*8);
#pragma unroll
        for (int mi = 0; mi < 4; ++mi)
          acc[mi][ni] = __builtin_amdgcn_mfma_f32_16x16x32_bf16(af[mi], bfr, acc[mi][ni], 0, 0, 0);
      }
    }
    if (t+1 < NSTEP) writeB(cur ^ 1);
    __syncthreads();
    cur ^= 1;
  }

  float* obase = dst + (size_t)ks * ((size_t)B_SZ*NINST*D_OUTD)
               + ((size_t)b0 * NINST + i) * D_OUTD + o0;
#pragma unroll
  for (int mi = 0; mi < 4; ++mi)
#pragma unroll
    for (int ni = 0; ni < 4; ++ni) {
      const int colL = wc*64 + ni*16 + (lane & 15);
#pragma unroll
      for (int j = 0; j < 4; ++j) {
        const int rowL = wr*64 + mi*16 + (lane >> 4)*4 + j;
        obase[(size_t)rowL * (NINST*D_OUTD) + colL] = acc[mi][ni][j];
      }
    }
}

__global__ __launch_bounds__(256)
void reduce_kernel(const float* __restrict__ part, float* __restrict__ out, int nks)
{
  const int total = (B_SZ*NINST*D_OUTD) / 4;
  for (int v = blockIdx.x*256 + threadIdx.x; v < total; v += gridDim.x*256) {
    f32x4 s = ((const f32x4*)part)[v];
    for (int ks = 1; ks < nks; ++ks)
      s += ((const f32x4*)part)[(size_t)ks*total + v];
    ((f32x4*)out)[v] = s;
  }
}

extern "C" void kernel_launch(void* const* d_in, const int* in_sizes, int n_in,
                              void* d_out, int out_size, void* d_ws, size_t ws_size,
                              hipStream_t stream) {
  const float* x    = (const float*)d_in[0];
  const float* A    = (const float*)d_in[1];
  const float* Bm   = (const float*)d_in[2];
  const int*   mask = (const int*)d_in[3];

  const size_t innerB = (size_t)NINST * B_SZ * KTOT * 2;       // 64 MB
  const size_t xbfB   = (size_t)NINST * B_SZ * D_IN * 2;       // 4 MB
  const size_t gixB   = (size_t)NINST * CCOMP * 512 * 4;       // 512 KB
  const size_t cntB   = 4096;                                  // 1 KB padded
  const size_t partB  = (size_t)B_SZ * NINST * D_OUTD * 4;     // 8 MB per split

  char* p = (char*)d_ws;
  __bf16* inner = (__bf16*)p;             p += innerB;
  __bf16* xbf   = (__bf16*)p;             p += xbfB;
  int*    gidx  = (int*)p;                p += gixB;
  int*    cnts  = (int*)p;                p += cntB;
  const size_t used = (size_t)(p - (char*)d_ws);

  int nks = 1;
  if      (ws_size >= used + 4*partB) nks = 4;
  else if (ws_size >= used + 2*partB) nks = 2;
  float* part = (nks > 1) ? (float*)p : (float*)d_out;

  xcvt_kernel<<<dim3(1024), dim3(256), 0, stream>>>(x, xbf);
  maskscan_kernel<<<dim3(NINST*CCOMP), dim3(512), 0, stream>>>(mask, gidx, cnts);
  p1_kernel<<<dim3(2048), dim3(256), 0, stream>>>(xbf, A, gidx, cnts, inner);
  p2_kernel<<<dim3(128*nks), dim3(256), 0, stream>>>(inner, Bm, part, nks);
  if (nks > 1)
    reduce_kernel<<<dim3(512), dim3(256), 0, stream>>>(part, (float*)d_out, nks);
}

// Round 9
// 269.183 us; speedup vs baseline: 2.1484x; 1.0181x over previous
//
#include <hip/hip_runtime.h>
#include <hip/hip_bf16.h>
#include <stdint.h>

#define B_SZ   512
#define NINST  4
#define D_IN   1024
#define D_OUTD 1024
#define CCOMP  64
#define MRANK  256
#define KTOT   (CCOMP*MRANK)   // 16384

typedef __attribute__((ext_vector_type(4))) float  f32x4;
typedef __attribute__((ext_vector_type(8))) __bf16 bf16x8;
typedef __attribute__((ext_vector_type(4))) __bf16 bf16x4;

__device__ inline void gload_lds16(const __bf16* g, __bf16* l) {
  __builtin_amdgcn_global_load_lds(
      (const __attribute__((address_space(1))) void*)g,
      (__attribute__((address_space(3))) void*)l, 16, 0, 0);
}

// ---------------------------------------------------------------------------
// Prepass: xbf[i][b][k] = bf16(x[b][i][k]).  12 MB traffic, ~3 us.
// ---------------------------------------------------------------------------
__global__ __launch_bounds__(256)
void xcvt_kernel(const float* __restrict__ x, __bf16* __restrict__ xbf)
{
  const int total = (B_SZ*NINST*D_IN) / 4;
  for (int v = blockIdx.x*256 + threadIdx.x; v < total; v += gridDim.x*256) {
    const int k4 = v & 255;
    const int i  = (v >> 8) & 3;
    const int b  = v >> 10;
    f32x4 f = ((const f32x4*)x)[v];
    bf16x4 h; h[0]=(__bf16)f.x; h[1]=(__bf16)f.y; h[2]=(__bf16)f.z; h[3]=(__bf16)f.w;
    ((bf16x4*)xbf)[((size_t)i*B_SZ + b)*256 + k4] = h;
  }
}

// ---------------------------------------------------------------------------
// Phase 1, seg-batched (p2 skeleton): each block owns 4 consecutive ic
// (same i -> same X rows) and runs ONE continuous 64-step dbuf pipeline;
// kt>>4 selects the A panel, kt&15 the K-tile.  Tile 128(b) x 128(m), BK=64,
// 256 thr / 4 waves, smem exactly 64 KB -> 2 blocks/CU, grid 512 (1 round).
// Per-seg epilogue: direct masked scalar stores (no LDS, no barrier) + re-zero.
// ---------------------------------------------------------------------------
__global__ __launch_bounds__(256, 2)
void p1_kernel(const __bf16* __restrict__ xbf, const float* __restrict__ A,
               const int* __restrict__ mask, __bf16* __restrict__ inner)
{
  const int bid = blockIdx.x;
  const int L   = (bid & 7) * 64 + (bid >> 3);   // XCD-chunked, grid 512
  const int bt  = L & 3;
  const int mt  = (L >> 2) & 1;
  const int icg = L >> 3;          // 0..63 -> ic0 = icg*4 (never straddles i)
  const int ic0 = icg * 4;
  const int i   = ic0 >> 6;
  const int c0  = ic0 & 63;
  const int b0  = bt * 128;
  const int m0  = mt * 128;

  const int tid  = threadIdx.x;
  const int lane = tid & 63;
  const int wid  = tid >> 6;       // 0..3
  const int wr   = wid >> 1;       // 0..1 : 64-row strip
  const int wc   = wid & 1;        // 0..1 : 64-col strip

  __shared__ __align__(16) char smem[65536];
  __bf16* Xs = (__bf16*)smem;             // [2][128][64]
  __bf16* As = (__bf16*)(smem + 32768);   // [2][128][64] m-major

  f32x4 acc[4][4];
#pragma unroll
  for (int a_ = 0; a_ < 4; ++a_)
#pragma unroll
    for (int b_ = 0; b_ < 4; ++b_)
      acc[a_][b_] = (f32x4){0.f, 0.f, 0.f, 0.f};

  const __bf16* xbase  = xbf + ((size_t)i * B_SZ + b0) * D_IN;
  const float*  Abase0 = A + (size_t)ic0 * D_IN * MRANK + m0;

  const int bo = tid & 127;        // A column m (within 128)
  const int bg = tid >> 7;         // 0..1 -> 4 k-octets each

  float areg[4][8];

  auto stageXs = [&](int buf, int kt) {
#pragma unroll
    for (int q = 0; q < 4; ++q) {
      const int ci  = wid*4 + q;                 // 0..15, wave-uniform
      const int row = ci*8 + (lane >> 3);
      const int kch = (lane & 7) ^ (row & 7);    // pre-swizzled source
      gload_lds16(xbase + (size_t)row * D_IN + (kt & 15)*64 + kch*8,
                  Xs + buf*8192 + ci*512);
    }
  };
  auto loadA = [&](int kt) {
    const float* Ab = Abase0 + (size_t)(kt >> 4) * D_IN * MRANK;
#pragma unroll
    for (int q = 0; q < 4; ++q)
#pragma unroll
      for (int j = 0; j < 8; ++j)
        areg[q][j] = Ab[(size_t)((kt & 15)*64 + (bg*4+q)*8 + j)*MRANK + bo];
  };
  auto writeA = [&](int buf) {
#pragma unroll
    for (int q = 0; q < 4; ++q) {
      const int oct = bg*4 + q;
      bf16x8 h;
#pragma unroll
      for (int j = 0; j < 8; ++j) h[j] = (__bf16)areg[q][j];
      *(bf16x8*)(As + buf*8192 + bo*64 + ((oct ^ (bo & 7)))*8) = h;
    }
  };

  stageXs(0, 0); loadA(0); writeA(0);
  __syncthreads();

  int cur = 0;
  for (int kt = 0; kt < 64; ++kt) {
    if (kt+1 < 64) { stageXs(cur ^ 1, kt+1); loadA(kt+1); }
#pragma unroll
    for (int kk = 0; kk < 2; ++kk) {
      const int oct = kk*4 + (lane >> 4);
      bf16x8 af[4];
#pragma unroll
      for (int mi = 0; mi < 4; ++mi) {
        const int row = wr*64 + mi*16 + (lane & 15);
        af[mi] = *(const bf16x8*)(Xs + cur*8192 + row*64 + ((oct ^ (row & 7)))*8);
      }
#pragma unroll
      for (int ni = 0; ni < 4; ++ni) {
        const int col = wc*64 + ni*16 + (lane & 15);
        bf16x8 bfr = *(const bf16x8*)(As + cur*8192 + col*64 + ((oct ^ (col & 7)))*8);
#pragma unroll
        for (int mi = 0; mi < 4; ++mi)
          acc[mi][ni] = __builtin_amdgcn_mfma_f32_16x16x32_bf16(af[mi], bfr, acc[mi][ni], 0, 0, 0);
      }
    }
    if ((kt & 15) == 15) {
      // ---- per-seg epilogue: masked direct stores, re-zero acc ----
      const int c = c0 + (kt >> 4);
      __bf16* obase = inner + ((size_t)i * B_SZ + b0) * KTOT + (size_t)c * MRANK + m0;
      float mv[16];
#pragma unroll
      for (int mi = 0; mi < 4; ++mi)
#pragma unroll
        for (int j = 0; j < 4; ++j) {
          const int row = wr*64 + mi*16 + (lane >> 4)*4 + j;
          mv[mi*4+j] = (float)mask[(size_t)(b0 + row) * (NINST*CCOMP) + i*CCOMP + c];
        }
#pragma unroll
      for (int mi = 0; mi < 4; ++mi)
#pragma unroll
        for (int ni = 0; ni < 4; ++ni) {
          const int colL = wc*64 + ni*16 + (lane & 15);
#pragma unroll
          for (int j = 0; j < 4; ++j) {
            const int rowL = wr*64 + mi*16 + (lane >> 4)*4 + j;
            obase[(size_t)rowL * KTOT + colL] = (__bf16)(acc[mi][ni][j] * mv[mi*4+j]);
          }
#pragma unroll
          for (int j = 0; j < 4; ++j) acc[mi][ni][j] = 0.f;
        }
    }
    if (kt+1 < 64) writeA(cur ^ 1);
    __syncthreads();
    cur ^= 1;
  }
}

// ---------------------------------------------------------------------------
// Phase 2: part[ks][b][i][o] = sum_{K slice} inner . Bflat.  (unchanged R7/R8)
// 256 thr / 4 waves, tile 128(b) x 128(o), BK=64, dbuf, LDS 64 KB, 2/CU.
// ---------------------------------------------------------------------------
__global__ __launch_bounds__(256, 2)
void p2_kernel(const __bf16* __restrict__ inner, const float* __restrict__ Bm,
               float* __restrict__ dst, int nks)
{
  const int bid = blockIdx.x;
  const int L   = (bid & 7) * (gridDim.x >> 3) + (bid >> 3);
  const int bt  = L & 3;
  const int nt  = (L >> 2) & 7;
  const int rest = L >> 5;         // i*nks + ks
  const int ks  = rest % nks;
  const int i   = rest / nks;
  const int b0  = bt * 128;
  const int o0  = nt * 128;
  const int NSTEP = (KTOT/64) / nks;
  const int kb0   = ks * NSTEP;

  const int tid  = threadIdx.x;
  const int lane = tid & 63;
  const int wid  = tid >> 6;
  const int wr   = wid >> 1;
  const int wc   = wid & 1;

  __shared__ __align__(16) char smem[65536];
  __bf16* Is = (__bf16*)smem;             // [2][128][64]
  __bf16* Bs = (__bf16*)(smem + 32768);   // [2][128][64] n-major

  f32x4 acc[4][4];
#pragma unroll
  for (int a_ = 0; a_ < 4; ++a_)
#pragma unroll
    for (int b_ = 0; b_ < 4; ++b_)
      acc[a_][b_] = (f32x4){0.f, 0.f, 0.f, 0.f};

  const __bf16* ibase = inner + ((size_t)i * B_SZ + b0) * KTOT;
  const float*  Bbase = Bm + (size_t)i * KTOT * D_OUTD + o0;

  const int bo = tid & 127;
  const int bg = tid >> 7;

  float breg[4][8];

  auto stageIs = [&](int buf, int kt) {
#pragma unroll
    for (int q = 0; q < 4; ++q) {
      const int ci  = wid*4 + q;
      const int row = ci*8 + (lane >> 3);
      const int kch = (lane & 7) ^ (row & 7);
      gload_lds16(ibase + (size_t)row * KTOT + kt*64 + kch*8,
                  Is + buf*8192 + ci*512);
    }
  };
  auto loadB = [&](int kt) {
#pragma unroll
    for (int q = 0; q < 4; ++q)
#pragma unroll
      for (int j = 0; j < 8; ++j)
        breg[q][j] = Bbase[(size_t)(kt*64 + (bg*4+q)*8 + j)*D_OUTD + bo];
  };
  auto writeB = [&](int buf) {
#pragma unroll
    for (int q = 0; q < 4; ++q) {
      const int oct = bg*4 + q;
      bf16x8 h;
#pragma unroll
      for (int j = 0; j < 8; ++j) h[j] = (__bf16)breg[q][j];
      *(bf16x8*)(Bs + buf*8192 + bo*64 + ((oct ^ (bo & 7)))*8) = h;
    }
  };

  stageIs(0, kb0); loadB(kb0); writeB(0);
  __syncthreads();

  int cur = 0;
  for (int t = 0; t < NSTEP; ++t) {
    if (t+1 < NSTEP) { stageIs(cur ^ 1, kb0 + t + 1); loadB(kb0 + t + 1); }
#pragma unroll
    for (int kk = 0; kk < 2; ++kk) {
      const int oct = kk*4 + (lane >> 4);
      bf16x8 af[4];
#pragma unroll
      for (int mi = 0; mi < 4; ++mi) {
        const int row = wr*64 + mi*16 + (lane & 15);
        af[mi] = *(const bf16x8*)(Is + cur*8192 + row*64 + ((oct ^ (row & 7)))*8);
      }
#pragma unroll
      for (int ni = 0; ni < 4; ++ni) {
        const int col = wc*64 + ni*16 + (lane & 15);
        bf16x8 bfr = *(const bf16x8*)(Bs + cur*8192 + col*64 + ((oct ^ (col & 7)))*8);
#pragma unroll
        for (int mi = 0; mi < 4; ++mi)
          acc[mi][ni] = __builtin_amdgcn_mfma_f32_16x16x32_bf16(af[mi], bfr, acc[mi][ni], 0, 0, 0);
      }
    }
    if (t+1 < NSTEP) writeB(cur ^ 1);
    __syncthreads();
    cur ^= 1;
  }

  float* obase = dst + (size_t)ks * ((size_t)B_SZ*NINST*D_OUTD)
               + ((size_t)b0 * NINST + i) * D_OUTD + o0;
#pragma unroll
  for (int mi = 0; mi < 4; ++mi)
#pragma unroll
    for (int ni = 0; ni < 4; ++ni) {
      const int colL = wc*64 + ni*16 + (lane & 15);
#pragma unroll
      for (int j = 0; j < 4; ++j) {
        const int rowL = wr*64 + mi*16 + (lane >> 4)*4 + j;
        obase[(size_t)rowL * (NINST*D_OUTD) + colL] = acc[mi][ni][j];
      }
    }
}

__global__ __launch_bounds__(256)
void reduce_kernel(const float* __restrict__ part, float* __restrict__ out, int nks)
{
  const int total = (B_SZ*NINST*D_OUTD) / 4;
  for (int v = blockIdx.x*256 + threadIdx.x; v < total; v += gridDim.x*256) {
    f32x4 s = ((const f32x4*)part)[v];
    for (int ks = 1; ks < nks; ++ks)
      s += ((const f32x4*)part)[(size_t)ks*total + v];
    ((f32x4*)out)[v] = s;
  }
}

extern "C" void kernel_launch(void* const* d_in, const int* in_sizes, int n_in,
                              void* d_out, int out_size, void* d_ws, size_t ws_size,
                              hipStream_t stream) {
  const float* x    = (const float*)d_in[0];
  const float* A    = (const float*)d_in[1];
  const float* Bm   = (const float*)d_in[2];
  const int*   mask = (const int*)d_in[3];

  const size_t innerB = (size_t)NINST * B_SZ * KTOT * 2;       // 64 MB
  const size_t xbfB   = (size_t)NINST * B_SZ * D_IN * 2;       // 4 MB
  const size_t partB  = (size_t)B_SZ * NINST * D_OUTD * 4;     // 8 MB per split

  char* p = (char*)d_ws;
  __bf16* inner = (__bf16*)p;             p += innerB;
  __bf16* xbf   = (__bf16*)p;             p += xbfB;
  const size_t used = (size_t)(p - (char*)d_ws);

  int nks = 1;
  if      (ws_size >= used + 4*partB) nks = 4;
  else if (ws_size >= used + 2*partB) nks = 2;
  float* part = (nks > 1) ? (float*)p : (float*)d_out;

  xcvt_kernel<<<dim3(1024),  dim3(256), 0, stream>>>(x, xbf);
  p1_kernel<<<dim3(512),     dim3(256), 0, stream>>>(xbf, A, mask, inner);
  p2_kernel<<<dim3(128*nks), dim3(256), 0, stream>>>(inner, Bm, part, nks);
  if (nks > 1)
    reduce_kernel<<<dim3(512), dim3(256), 0, stream>>>(part, (float*)d_out, nks);
}